// Round 15
// baseline (185.871 us; speedup 1.0000x reference)
//
#include <hip/hip_runtime.h>
#include <math.h>

#define D_MODEL 1024
#define NHEADS  16
#define NKV     4
#define HDIM    64
#define KVDIM   256
#define BB      2
#define NN      2048
#define MROWS   (BB*NN)        // 4096
#define QKVN    1536           // 1024 + 256 + 256
#define NTASK   (MROWS*NHEADS) // 65536
#define NSPLIT  2
#define KVBLK   128
#define NTILE   ((NN/NSPLIT)/KVBLK)   // 8

typedef unsigned short ushort_t;
typedef unsigned int uint_t;
typedef float    f32x4 __attribute__((ext_vector_type(4)));
typedef _Float16 h16x8 __attribute__((ext_vector_type(8)));
typedef _Float16 h16x4 __attribute__((ext_vector_type(4)));
typedef __fp16   fp16x2 __attribute__((ext_vector_type(2)));

#define MFMAH(A,B,C)  __builtin_amdgcn_mfma_f32_16x16x32_f16((A),(B),(C),0,0,0)
// NOTE spelling: carried-forward GCN-era intrinsic has NO underscore before f16
#define MFMA16(A,B,C) __builtin_amdgcn_mfma_f32_16x16x16f16((A),(B),(C),0,0,0)
// raw v_exp_f32 (1 instr) -- libm exp2f carries a ~6-instr denormal fixup
#define EXP2(x) __builtin_amdgcn_exp2f(x)

// async global->LDS, 16B per lane; LDS dest = wave-uniform base + lane*16
#define GLDS(gp, lp) __builtin_amdgcn_global_load_lds( \
    (const __attribute__((address_space(1))) void*)(gp), \
    (__attribute__((address_space(3))) void*)(lp), 16, 0, 0)

__device__ __forceinline__ ushort_t f2h(float f) {
    _Float16 h = (_Float16)f;
    return *(ushort_t*)&h;
}
__device__ __forceinline__ float h2f(ushort_t u) {
    return (float)(*(const _Float16*)&u);
}
// two fp32 -> packed f16x2, single v_cvt_pkrtz_f16_f32
__device__ __forceinline__ uint_t pk2h(float a, float b) {
    fp16x2 v = __builtin_amdgcn_cvt_pkrtz(a, b);
    return *(uint_t*)&v;
}

// ---------------------------------------------------------------------------
// Fused prep: cast x->f16 (blocks [0,4096)) + 4 weight transpose-casts
// (blocks [4096,6656)). K-weight columns are PERMUTED within each head:
// rho(2j) = p, rho(2j+1) = p+16 with p = (j<16)? j : j+16 -- so the rope
// pair (2j,2j+1) lands in the SAME LANE (nt=0/nt=1 registers) of the QKV
// GEMM epilogue, making K-rope lane-local there.
// ---------------------------------------------------------------------------
__global__ __launch_bounds__(256)
void prep_kernel(const float* __restrict__ x, const float* __restrict__ Wq,
                 const float* __restrict__ Wk, const float* __restrict__ Wv,
                 const float* __restrict__ Wo, ushort_t* __restrict__ xb,
                 ushort_t* __restrict__ WqkvT, ushort_t* __restrict__ WoT)
{
    __shared__ float T[32][33];
    int blk = blockIdx.x;
    if (blk < 4096) {                      // cast: 4096*256*4 = 4M elements
        const int i = blk * 256 + threadIdx.x;
        float4 v = ((const float4*)x)[i];
        uint2 o;
        o.x = pk2h(v.x, v.y);
        o.y = pk2h(v.z, v.w);
        ((uint2*)xb)[i] = o;
        return;
    }
    blk -= 4096;
    const float* src; ushort_t* dst; int N, bx, by; int kperm = 0;
    if (blk < 1024)      { src = Wq; dst = WqkvT;                            N = D_MODEL; bx = blk & 31; by = blk >> 5; }
    else if (blk < 1280) { blk -= 1024; src = Wk; dst = WqkvT + (size_t)1024 * D_MODEL; N = KVDIM; bx = blk & 7; by = blk >> 3; kperm = 1; }
    else if (blk < 1536) { blk -= 1280; src = Wv; dst = WqkvT + (size_t)1280 * D_MODEL; N = KVDIM; bx = blk & 7; by = blk >> 3; }
    else                 { blk -= 1536; src = Wo; dst = WoT;                 N = D_MODEL; bx = blk & 31; by = blk >> 5; }
    const int tx = threadIdx.x & 31, ty = threadIdx.x >> 5;
    const int n0 = bx * 32, k0 = by * 32;
#pragma unroll
    for (int i = 0; i < 4; i++)
        T[ty + i * 8][tx] = src[(size_t)(k0 + ty + i * 8) * N + n0 + tx];
    __syncthreads();
#pragma unroll
    for (int i = 0; i < 4; i++) {
        int c = n0 + ty + i * 8;
        if (kperm) {
            const int hd = c >> 6, ch = c & 63;
            const int j = ch >> 1, odd = ch & 1;
            const int p = ((j < 16) ? j : j + 16) + odd * 16;
            c = hd * 64 + p;
        }
        dst[(size_t)c * D_MODEL + k0 + tx] = f2h(T[tx][ty + i * 8]);
    }
}

// ---------------------------------------------------------------------------
// f16 MFMA GEMM for QKV, 128x64 tile, 4-slot LDS ring (round-13 proven
// K-loop, untouched). Round-27 epilogue fusion by output region:
//   cols [0,1024): Q   -> Qh (stride 1024, raw; attn applies Q-rope)
//   cols [1024,1280): K -> rope applied IN-REGISTER (pairs are lane-local
//                        thanks to prep's rho permutation) -> Kb layout
//   cols [1280,1536): V -> transposed write -> Vt (1 uint2 per fragment)
// Deletes the ropevt kernel + QKVh K/V round-trip.
// ---------------------------------------------------------------------------
__global__ __launch_bounds__(256)
void gemm_qkv(const ushort_t* __restrict__ A, const ushort_t* __restrict__ Bt,
              const float* __restrict__ Cos, const float* __restrict__ Sin,
              ushort_t* __restrict__ Qh, ushort_t* __restrict__ Kb,
              ushort_t* __restrict__ Vt)
{
    __shared__ ushort_t As[4][128 * 32];
    __shared__ ushort_t Bs[4][64 * 32];

    const int K = D_MODEL;
    const int tid  = threadIdx.x;
    const int wave = tid >> 6, lane = tid & 63;
    const int quad = lane >> 4, l16 = lane & 15;
    const int rowBase = blockIdx.y * 128, colBase = blockIdx.x * 64;
    const int wm = (wave >> 1) * 64, wn = (wave & 1) * 32;

    f32x4 acc[4][2];
    const f32x4 zz = {0.f, 0.f, 0.f, 0.f};
#pragma unroll
    for (int i = 0; i < 4; i++)
#pragma unroll
        for (int j = 0; j < 2; j++) acc[i][j] = zz;

    const int sr = wave * 32 + (lane >> 2);
    const int sc = ((lane & 3) ^ ((lane >> 3) & 3)) * 8;
    const ushort_t* Ag0 = A + (size_t)(rowBase + sr) * K + sc;
    const ushort_t* Ag1 = A + (size_t)(rowBase + sr + 16) * K + sc;
    const int segA0 = (wave * 2 + 0) * 512, segA1 = (wave * 2 + 1) * 512;
    const int br = wave * 16 + (lane >> 2);
    const ushort_t* Bg0 = Bt + (size_t)(colBase + br) * K + sc;
    const int segB = wave * 512;

    const int fcol = (quad ^ ((l16 >> 1) & 3)) * 8;

    // prologue: stage slots 0 (k=0) and 1 (k=32)
    GLDS(Ag0, &As[0][segA0]);
    GLDS(Ag1, &As[0][segA1]);
    GLDS(Bg0, &Bs[0][segB]);
    GLDS(Ag0 + 32, &As[1][segA0]);
    GLDS(Ag1 + 32, &As[1][segA1]);
    GLDS(Bg0 + 32, &Bs[1][segB]);

#define QKV_COMPUTE(curslot) { \
        h16x8 af[4], bf[2]; \
        _Pragma("unroll") \
        for (int mt = 0; mt < 4; mt++) \
            af[mt] = *(const h16x8*)&As[curslot][(wm + mt * 16 + l16) * 32 + fcol]; \
        _Pragma("unroll") \
        for (int nt = 0; nt < 2; nt++) \
            bf[nt] = *(const h16x8*)&Bs[curslot][(wn + nt * 16 + l16) * 32 + fcol]; \
        _Pragma("unroll") \
        for (int mt = 0; mt < 4; mt++) \
            _Pragma("unroll") \
            for (int nt = 0; nt < 2; nt++) \
                acc[mt][nt] = MFMAH(af[mt], bf[nt], acc[mt][nt]); \
    }

    for (int k0 = 0; k0 < K; k0 += 64) {
        const int s0 = (k0 >> 5) & 3, s1 = (s0 + 1) & 3;
        const int s2 = (s0 + 2) & 3, s3 = (s0 + 3) & 3;
        __syncthreads();   // slots s0,s1 staged (issued last pair) now drained
        if (k0 + 64 < K) {
            GLDS(Ag0 + k0 + 64, &As[s2][segA0]);
            GLDS(Ag1 + k0 + 64, &As[s2][segA1]);
            GLDS(Bg0 + k0 + 64, &Bs[s2][segB]);
        }
        if (k0 + 96 < K) {
            GLDS(Ag0 + k0 + 96, &As[s3][segA0]);
            GLDS(Ag1 + k0 + 96, &As[s3][segA1]);
            GLDS(Bg0 + k0 + 96, &Bs[s3][segB]);
        }
        QKV_COMPUTE(s0);
        QKV_COMPUTE(s1);
    }
#undef QKV_COMPUTE

    if (colBase < 1024) {
        // ---- Q region: plain store to Qh (stride 1024)
#pragma unroll
        for (int mt = 0; mt < 4; mt++)
#pragma unroll
            for (int nt = 0; nt < 2; nt++) {
                const int row = rowBase + wm + mt * 16 + quad * 4;
                const int col = colBase + wn + nt * 16 + l16;
#pragma unroll
                for (int r = 0; r < 4; r++)
                    Qh[(size_t)(row + r) * D_MODEL + col] = f2h(acc[mt][nt][r]);
            }
    } else if (colBase < 1280) {
        // ---- K region: in-register rope (pair = acc[mt][0]/acc[mt][1])
        const int h = (colBase - 1024) >> 6;
        const int p = wn + l16;                 // [0,16) u [32,48)
        const int j = (p < 32) ? p : p - 16;    // [0,32)
#pragma unroll
        for (int mt = 0; mt < 4; mt++) {
            const int rowm = rowBase + wm + mt * 16 + quad * 4;
            const int bb = rowm >> 11, nb = rowm & (NN - 1);
            ushort_t* dstK = Kb + ((size_t)(bb * 4 + h) * NN) * 64;
#pragma unroll
            for (int r = 0; r < 4; r++) {
                const int n = nb + r;
                const float c = Cos[n * 32 + j], s = Sin[n * 32 + j];
                const float e = acc[mt][0][r], o = acc[mt][1][r];
                ushort_t* dk = dstK + (size_t)n * 64;
                dk[j]      = f2h(e * c - o * s);
                dk[j + 32] = f2h(e * s + o * c);
            }
        }
    } else {
        // ---- V region: transposed store to Vt (one uint2 per fragment)
        const int v0 = colBase - 1280;
#pragma unroll
        for (int mt = 0; mt < 4; mt++)
#pragma unroll
            for (int nt = 0; nt < 2; nt++) {
                const int d = v0 + wn + nt * 16 + l16;
                const int rowm = rowBase + wm + mt * 16 + quad * 4;
                const int bb = rowm >> 11, nb = rowm & (NN - 1);
                uint2 pk;
                pk.x = pk2h(acc[mt][nt][0], acc[mt][nt][1]);
                pk.y = pk2h(acc[mt][nt][2], acc[mt][nt][3]);
                *(uint2*)&Vt[((size_t)(bb * 256 + d)) * NN + nb] = pk;
            }
    }
}

// ---------------------------------------------------------------------------
// MFMA flash attention (round-14 structure) + s_setprio(1) around the PV
// MFMA cluster (T5: helps when co-resident blocks are at different phases;
// our 2 blocks/CU are independent). Q now read from Qh (stride 1024).
// ---------------------------------------------------------------------------
__global__ __launch_bounds__(256)
void attn_mfma(const ushort_t* __restrict__ Qh, const float* __restrict__ Cos,
               const float* __restrict__ Sin, const ushort_t* __restrict__ Kb,
               const ushort_t* __restrict__ Vt, ushort_t* __restrict__ Pnum,
               float* __restrict__ Pl)
{
    const int qt = blockIdx.x, h = blockIdx.y;
    const int b = blockIdx.z >> 1, chunk = blockIdx.z & 1;
    const int kvh = h >> 2;
    const int tid = threadIdx.x;
    const int wave = tid >> 6, lane = tid & 63;
    const int quad = lane >> 4, l16 = lane & 15;

    __shared__ ushort_t Ks[2][128][64];
    __shared__ ushort_t Vs[2][64][128];

    const int row0 = qt * 256 + wave * 64;
    const float SC = 0.125f * 1.44269504f;

    h16x8 qf[4][2];
#pragma unroll
    for (int mt = 0; mt < 4; mt++) {
        const int n = row0 + mt * 16 + l16;
        // pre-rope Q row: cols h*64 + [2j, 2j+1] for j = quad*8 + i
        const uint_t* pr =
            (const uint_t*)(Qh + (size_t)(b * NN + n) * D_MODEL + h * 64) + quad * 8;
        uint4 pa = *(const uint4*)pr;
        uint4 pc = *(const uint4*)(pr + 4);
        const uint_t pk[8] = {pa.x, pa.y, pa.z, pa.w, pc.x, pc.y, pc.z, pc.w};
        const float4 c0 = *(const float4*)&Cos[(size_t)n * 32 + quad * 8];
        const float4 c1 = *(const float4*)&Cos[(size_t)n * 32 + quad * 8 + 4];
        const float4 s0 = *(const float4*)&Sin[(size_t)n * 32 + quad * 8];
        const float4 s1 = *(const float4*)&Sin[(size_t)n * 32 + quad * 8 + 4];
        const float cc[8] = {c0.x, c0.y, c0.z, c0.w, c1.x, c1.y, c1.z, c1.w};
        const float ss[8] = {s0.x, s0.y, s0.z, s0.w, s1.x, s1.y, s1.z, s1.w};
#pragma unroll
        for (int i = 0; i < 8; i++) {
            const float e = h2f((ushort_t)pk[i]);
            const float o = h2f((ushort_t)(pk[i] >> 16));
            qf[mt][0][i] = (_Float16)((e * cc[i] - o * ss[i]) * SC);
            qf[mt][1][i] = (_Float16)((e * ss[i] + o * cc[i]) * SC);
        }
    }

    h16x4 ones;
#pragma unroll
    for (int i = 0; i < 4; i++) ones[i] = (_Float16)1.0f;

    const ushort_t* kbase = Kb + (size_t)(b * 4 + kvh) * NN * 64;
    const ushort_t* vbase = Vt + (size_t)(b * 256 + kvh * 64) * NN;
    const int key_lo = chunk * (NN / NSPLIT);          // 1024-key chunk
    const int rot = (qt + ((h & 3) << 2)) & (NTILE - 1);

    // staging lane constants (GLDS: dest = wave-uniform base + lane*16)
    const int krow = (wave << 3) + (lane >> 3);        // row within 32-row group
    const int kseg = (lane & 7) ^ (krow & 7);          // pre-swizzled global seg
    const ushort_t* kp_lane = kbase + (size_t)krow * 64 + kseg * 8;
    const int vrow = (wave << 2) + (lane >> 4);        // row within 16-row group
    const int vseg = (lane & 15) ^ (vrow & 7);
    const ushort_t* vp_lane = vbase + (size_t)vrow * NN + vseg * 8;

#define STAGE(key, bufidx) { \
        _Pragma("unroll") \
        for (int i = 0; i < 4; i++) { \
            GLDS(kp_lane + (size_t)((key) + i * 32) * 64, &Ks[bufidx][i * 32 + (wave << 3)][0]); \
            GLDS(vp_lane + (size_t)(i * 16) * NN + (key), &Vs[bufidx][i * 16 + (wave << 2)][0]); \
        } \
    }

    const f32x4 zz = {0.f, 0.f, 0.f, 0.f};
    f32x4 o[4][4];
#pragma unroll
    for (int mt = 0; mt < 4; mt++)
#pragma unroll
        for (int dt = 0; dt < 4; dt++) o[mt][dt] = zz;
    f32x4 lsum[4];
#pragma unroll
    for (int mt = 0; mt < 4; mt++) lsum[mt] = zz;

    // prologue: stage tile 0 into buf 0
    STAGE(key_lo + rot * KVBLK, 0);

    const int kswz = l16 & 7;

    for (int t = 0; t < NTILE; t++) {
        const int cur = t & 1, nxt = cur ^ 1;
        __syncthreads();   // drains GLDS for buf[cur]; prev compute (buf[nxt]) done
        if (t < NTILE - 1) {
            const int kn = key_lo + ((rot + t + 1) & (NTILE - 1)) * KVBLK;
            STAGE(kn, nxt);   // lands during compute below, drained next barrier
        }

        // ---- fused per-kt: S^T = K Q^T -> exp2 -> pack -> PV (K=16, P in regs)
#pragma unroll
        for (int kt = 0; kt < 8; kt++) {
            h16x8 kf0 = *(const h16x8*)&Ks[cur][kt * 16 + l16][(quad ^ kswz) << 3];
            h16x8 kf1 = *(const h16x8*)&Ks[cur][kt * 16 + l16][((4 + quad) ^ kswz) << 3];
            // V fragments: global col kt*16+quad*4 -> seg 2kt+(quad>>1), half quad&1
            h16x4 va[4];
#pragma unroll
            for (int dt = 0; dt < 4; dt++)
                va[dt] = *(const h16x4*)&Vs[cur][dt * 16 + l16]
                    [(((kt * 2 + (quad >> 1)) ^ kswz) << 3) + ((quad & 1) << 2)];

            uint2 pb[4];
#pragma unroll
            for (int mt = 0; mt < 4; mt++) {
                f32x4 st = MFMAH(kf0, qf[mt][0], zz);
                st = MFMAH(kf1, qf[mt][1], st);
                pb[mt].x = pk2h(EXP2(st[0]), EXP2(st[1]));
                pb[mt].y = pk2h(EXP2(st[2]), EXP2(st[3]));
            }
            __builtin_amdgcn_s_setprio(1);
#pragma unroll
            for (int mt = 0; mt < 4; mt++) {
                const h16x4 pbv = *(const h16x4*)&pb[mt];
#pragma unroll
                for (int dt = 0; dt < 4; dt++)
                    o[mt][dt] = MFMA16(va[dt], pbv, o[mt][dt]);
                lsum[mt] = MFMA16(ones, pbv, lsum[mt]);
            }
            __builtin_amdgcn_s_setprio(0);
        }
    }
#undef STAGE

    const size_t task0 = (size_t)(b * 16 + h) * NN + row0;
    ushort_t* np = Pnum + ((size_t)chunk * NTASK + task0) * 64;
#pragma unroll
    for (int mt = 0; mt < 4; mt++) {
        const float lt = lsum[mt][0];    // denom for q=l16 (rows identical)
        const float inv = 1.0f / lt;
#pragma unroll
        for (int dt = 0; dt < 4; dt++) {
            f32x4 v = o[mt][dt];
            uint2 pk;
            pk.x = pk2h(v[0] * inv, v[1] * inv);
            pk.y = pk2h(v[2] * inv, v[3] * inv);
            *(uint2*)&np[(size_t)(mt * 16 + l16) * 64 + dt * 16 + quad * 4] = pk;
        }
        if (quad == 0)
            Pl[(size_t)chunk * NTASK + task0 + mt * 16 + l16] = lt;
    }
}

// ---------------------------------------------------------------------------
// Split-K combine (2-way) + relayout to plain [row][D_MODEL] f16 matrix.
// ---------------------------------------------------------------------------
__global__ __launch_bounds__(256)
void combine_kernel(const ushort_t* __restrict__ Pnum, const float* __restrict__ Pl,
                    ushort_t* __restrict__ Ob)
{
    const uint_t i = blockIdx.x * 256 + threadIdx.x;   // 8-elem group, 524288 total
    const int row = i >> 7;            // 128 groups per 1024-col row
    const int g = i & 127;
    const int col0 = g * 8;
    const int h = col0 >> 6, d = col0 & 63;
    const int b = row >> 11, n = row & (NN - 1);
    const size_t task = ((size_t)(b * 16 + h) << 11) + n;

    float l[NSPLIT], tot = 0.f;
#pragma unroll
    for (int c = 0; c < NSPLIT; c++) { l[c] = Pl[(size_t)c * NTASK + task]; tot += l[c]; }
    const float inv = 1.f / tot;

    uint4 in[NSPLIT];
#pragma unroll
    for (int c = 0; c < NSPLIT; c++)
        in[c] = *(const uint4*)&Pnum[((size_t)c * NTASK + task) * 64 + d];

    uint4 out;
    uint_t* po = (uint_t*)&out;
#pragma unroll
    for (int j = 0; j < 4; j++) {
        float x = 0.f, y = 0.f;
#pragma unroll
        for (int c = 0; c < NSPLIT; c++) {
            const float w = l[c] * inv;
            fp16x2 u = *(const fp16x2*)&((const uint_t*)&in[c])[j];
            x += w * (float)u.x;
            y += w * (float)u.y;
        }
        po[j] = pk2h(x, y);
    }
    *(uint4*)&Ob[(size_t)row * D_MODEL + col0] = out;
}

// ---------------------------------------------------------------------------
// Wo GEMM: plain f16 GEMM (fp32 out), 128x64 tile, 4-slot ring (round-13
// proven config).
// ---------------------------------------------------------------------------
__global__ __launch_bounds__(256)
void gemm_wo(const ushort_t* __restrict__ A, const ushort_t* __restrict__ Bt,
             float* __restrict__ C)
{
    __shared__ ushort_t As[4][128 * 32];
    __shared__ ushort_t Bs[4][64 * 32];

    const int tid  = threadIdx.x;
    const int wave = tid >> 6, lane = tid & 63;
    const int quad = lane >> 4, l16 = lane & 15;
    const int rowBase = blockIdx.y * 128, colBase = blockIdx.x * 64;
    const int wm = (wave >> 1) * 64, wn = (wave & 1) * 32;

    f32x4 acc[4][2];
    const f32x4 zz = {0.f, 0.f, 0.f, 0.f};
#pragma unroll
    for (int i = 0; i < 4; i++)
#pragma unroll
        for (int j = 0; j < 2; j++) acc[i][j] = zz;

    const int sr = wave * 32 + (lane >> 2);
    const int sc = ((lane & 3) ^ ((lane >> 3) & 3)) * 8;
    const ushort_t* Ag0 = A + (size_t)(rowBase + sr) * D_MODEL + sc;
    const ushort_t* Ag1 = A + (size_t)(rowBase + sr + 16) * D_MODEL + sc;
    const int segA0 = (wave * 2 + 0) * 512, segA1 = (wave * 2 + 1) * 512;
    const int br = wave * 16 + (lane >> 2);
    const ushort_t* Bg0 = Bt + (size_t)(colBase + br) * D_MODEL + sc;
    const int segB = wave * 512;

    const int fcol = (quad ^ ((l16 >> 1) & 3)) * 8;

    GLDS(Ag0, &As[0][segA0]);
    GLDS(Ag1, &As[0][segA1]);
    GLDS(Bg0, &Bs[0][segB]);
    GLDS(Ag0 + 32, &As[1][segA0]);
    GLDS(Ag1 + 32, &As[1][segA1]);
    GLDS(Bg0 + 32, &Bs[1][segB]);

#define WO_COMPUTE(curslot) { \
        h16x8 af[4], bf[2]; \
        _Pragma("unroll") \
        for (int mt = 0; mt < 4; mt++) \
            af[mt] = *(const h16x8*)&As[curslot][(wm + mt * 16 + l16) * 32 + fcol]; \
        _Pragma("unroll") \
        for (int nt = 0; nt < 2; nt++) \
            bf[nt] = *(const h16x8*)&Bs[curslot][(wn + nt * 16 + l16) * 32 + fcol]; \
        _Pragma("unroll") \
        for (int mt = 0; mt < 4; mt++) \
            _Pragma("unroll") \
            for (int nt = 0; nt < 2; nt++) \
                acc[mt][nt] = MFMAH(af[mt], bf[nt], acc[mt][nt]); \
    }

    for (int k0 = 0; k0 < D_MODEL; k0 += 64) {
        const int s0 = (k0 >> 5) & 3, s1 = (s0 + 1) & 3;
        const int s2 = (s0 + 2) & 3, s3 = (s0 + 3) & 3;
        __syncthreads();
        if (k0 + 64 < D_MODEL) {
            GLDS(Ag0 + k0 + 64, &As[s2][segA0]);
            GLDS(Ag1 + k0 + 64, &As[s2][segA1]);
            GLDS(Bg0 + k0 + 64, &Bs[s2][segB]);
        }
        if (k0 + 96 < D_MODEL) {
            GLDS(Ag0 + k0 + 96, &As[s3][segA0]);
            GLDS(Ag1 + k0 + 96, &As[s3][segA1]);
            GLDS(Bg0 + k0 + 96, &Bs[s3][segB]);
        }
        WO_COMPUTE(s0);
        WO_COMPUTE(s1);
    }
#undef WO_COMPUTE

#pragma unroll
    for (int mt = 0; mt < 4; mt++)
#pragma unroll
        for (int nt = 0; nt < 2; nt++) {
            const int row = rowBase + wm + mt * 16 + quad * 4;
            const int col = colBase + wn + nt * 16 + l16;
#pragma unroll
            for (int r = 0; r < 4; r++)
                C[(size_t)(row + r) * D_MODEL + col] = acc[mt][nt][r];
        }
}

// ---------------------------------------------------------------------------
extern "C" void kernel_launch(void* const* d_in, const int* in_sizes, int n_in,
                              void* d_out, int out_size, void* d_ws, size_t ws_size,
                              hipStream_t stream)
{
    const float* x    = (const float*)d_in[0];
    const float* cosp = (const float*)d_in[1];
    const float* sinp = (const float*)d_in[2];
    const float* Wq   = (const float*)d_in[3];
    const float* Wk   = (const float*)d_in[4];
    const float* Wv   = (const float*)d_in[5];
    const float* Wo   = (const float*)d_in[6];

    char* w = (char*)d_ws;
    ushort_t* xb     = (ushort_t*)w;                       w += (size_t)MROWS * D_MODEL * 2;
    ushort_t* WqkvT  = (ushort_t*)w;                       w += (size_t)QKVN * D_MODEL * 2;
    ushort_t* WoT    = (ushort_t*)w;                       w += (size_t)D_MODEL * D_MODEL * 2;
    ushort_t* Qh     = (ushort_t*)w;                       w += (size_t)MROWS * D_MODEL * 2;
    ushort_t* Kbuf   = (ushort_t*)w;                       w += (size_t)MROWS * KVDIM * 2;
    ushort_t* Vt     = (ushort_t*)w;                       w += (size_t)MROWS * KVDIM * 2;
    ushort_t* Obuf   = (ushort_t*)w;                       w += (size_t)MROWS * D_MODEL * 2;
    ushort_t* Pnum   = (ushort_t*)w;                       w += (size_t)NSPLIT * NTASK * 64 * 2;
    float*    Pl     = (float*)w;

    // --- fused prep (cast + 4 transposes, K-weight rho-permute): 1 dispatch
    prep_kernel<<<6656, 256, 0, stream>>>(x, Wq, Wk, Wv, Wo, xb, WqkvT, WoT);

    // --- fused QKV projection + K-rope + V-transpose epilogue (ropevt deleted)
    gemm_qkv<<<dim3(QKVN / 64, MROWS / 128), 256, 0, stream>>>(
        xb, WqkvT, cosp, sinp, Qh, Kbuf, Vt);

    // --- attention (split-K x2, GLDS+swizzle dbuf staging, setprio PV)
    attn_mfma<<<dim3(NN / 256, NHEADS, BB * NSPLIT), 256, 0, stream>>>(
        Qh, cosp, sinp, Kbuf, Vt, Pnum, Pl);

    // --- 2-way split-K combine -> plain f16 matrix
    combine_kernel<<<(MROWS * D_MODEL / 8) / 256, 256, 0, stream>>>(
        Pnum, Pl, Obuf);

    // --- output projection (plain GEMM, fp32 out), 128x64 tile, 4-slot ring
    gemm_wo<<<dim3(D_MODEL / 64, MROWS / 128), 256, 0, stream>>>(
        Obuf, WoT, (float*)d_out);
}

// Round 16
// 180.318 us; speedup vs baseline: 1.0308x; 1.0308x over previous
//
#include <hip/hip_runtime.h>
#include <math.h>

#define D_MODEL 1024
#define NHEADS  16
#define NKV     4
#define HDIM    64
#define KVDIM   256
#define BB      2
#define NN      2048
#define MROWS   (BB*NN)        // 4096
#define QKVN    1536           // 1024 + 256 + 256
#define NTASK   (MROWS*NHEADS) // 65536
#define NSPLIT  2
#define KVBLK   128
#define NTILE   ((NN/NSPLIT)/KVBLK)   // 8

typedef unsigned short ushort_t;
typedef unsigned int uint_t;
typedef float    f32x4 __attribute__((ext_vector_type(4)));
typedef _Float16 h16x8 __attribute__((ext_vector_type(8)));
typedef _Float16 h16x4 __attribute__((ext_vector_type(4)));
typedef __fp16   fp16x2 __attribute__((ext_vector_type(2)));

#define MFMAH(A,B,C)  __builtin_amdgcn_mfma_f32_16x16x32_f16((A),(B),(C),0,0,0)
// NOTE spelling: carried-forward GCN-era intrinsic has NO underscore before f16
#define MFMA16(A,B,C) __builtin_amdgcn_mfma_f32_16x16x16f16((A),(B),(C),0,0,0)
// raw v_exp_f32 (1 instr) -- libm exp2f carries a ~6-instr denormal fixup
#define EXP2(x) __builtin_amdgcn_exp2f(x)

// async global->LDS, 16B per lane; LDS dest = wave-uniform base + lane*16
#define GLDS(gp, lp) __builtin_amdgcn_global_load_lds( \
    (const __attribute__((address_space(1))) void*)(gp), \
    (__attribute__((address_space(3))) void*)(lp), 16, 0, 0)

__device__ __forceinline__ ushort_t f2h(float f) {
    _Float16 h = (_Float16)f;
    return *(ushort_t*)&h;
}
__device__ __forceinline__ float h2f(ushort_t u) {
    return (float)(*(const _Float16*)&u);
}
// two fp32 -> packed f16x2, single v_cvt_pkrtz_f16_f32
__device__ __forceinline__ uint_t pk2h(float a, float b) {
    fp16x2 v = __builtin_amdgcn_cvt_pkrtz(a, b);
    return *(uint_t*)&v;
}

// ---------------------------------------------------------------------------
// Fused prep: cast x->f16 (blocks [0,4096)) + 4 weight transpose-casts
// (blocks [4096,6656)). K-weight columns are PERMUTED within each head:
// rho(2j) = p, rho(2j+1) = p+16 with p = (j<16)? j : j+16 -- so the rope
// pair (2j,2j+1) lands in the SAME LANE (nt=0/nt=1 registers) of the QKV
// GEMM epilogue, making K-rope lane-local there.
// ---------------------------------------------------------------------------
__global__ __launch_bounds__(256)
void prep_kernel(const float* __restrict__ x, const float* __restrict__ Wq,
                 const float* __restrict__ Wk, const float* __restrict__ Wv,
                 const float* __restrict__ Wo, ushort_t* __restrict__ xb,
                 ushort_t* __restrict__ WqkvT, ushort_t* __restrict__ WoT)
{
    __shared__ float T[32][33];
    int blk = blockIdx.x;
    if (blk < 4096) {                      // cast: 4096*256*4 = 4M elements
        const int i = blk * 256 + threadIdx.x;
        float4 v = ((const float4*)x)[i];
        uint2 o;
        o.x = pk2h(v.x, v.y);
        o.y = pk2h(v.z, v.w);
        ((uint2*)xb)[i] = o;
        return;
    }
    blk -= 4096;
    const float* src; ushort_t* dst; int N, bx, by; int kperm = 0;
    if (blk < 1024)      { src = Wq; dst = WqkvT;                            N = D_MODEL; bx = blk & 31; by = blk >> 5; }
    else if (blk < 1280) { blk -= 1024; src = Wk; dst = WqkvT + (size_t)1024 * D_MODEL; N = KVDIM; bx = blk & 7; by = blk >> 3; kperm = 1; }
    else if (blk < 1536) { blk -= 1280; src = Wv; dst = WqkvT + (size_t)1280 * D_MODEL; N = KVDIM; bx = blk & 7; by = blk >> 3; }
    else                 { blk -= 1536; src = Wo; dst = WoT;                 N = D_MODEL; bx = blk & 31; by = blk >> 5; }
    const int tx = threadIdx.x & 31, ty = threadIdx.x >> 5;
    const int n0 = bx * 32, k0 = by * 32;
#pragma unroll
    for (int i = 0; i < 4; i++)
        T[ty + i * 8][tx] = src[(size_t)(k0 + ty + i * 8) * N + n0 + tx];
    __syncthreads();
#pragma unroll
    for (int i = 0; i < 4; i++) {
        int c = n0 + ty + i * 8;
        if (kperm) {
            const int hd = c >> 6, ch = c & 63;
            const int j = ch >> 1, odd = ch & 1;
            const int p = ((j < 16) ? j : j + 16) + odd * 16;
            c = hd * 64 + p;
        }
        dst[(size_t)c * D_MODEL + k0 + tx] = f2h(T[tx][ty + i * 8]);
    }
}

// ---------------------------------------------------------------------------
// f16 MFMA GEMM for QKV, 128x64 tile, 4-slot LDS ring. Round-28: XCD-aware
// blockIdx swizzle (1D grid 768 = 8 XCDs x 96): XCD x gets a contiguous
// work chunk -> 4 A-panels (1MB) + full B (3MB) fit its 4MB L2.
// Epilogue fusion unchanged: Q->Qh raw, K->rope in-register (rho-permuted
// weights), V->transposed Vt.
// ---------------------------------------------------------------------------
__global__ __launch_bounds__(256)
void gemm_qkv(const ushort_t* __restrict__ A, const ushort_t* __restrict__ Bt,
              const float* __restrict__ Cos, const float* __restrict__ Sin,
              ushort_t* __restrict__ Qh, ushort_t* __restrict__ Kb,
              ushort_t* __restrict__ Vt)
{
    __shared__ ushort_t As[4][128 * 32];
    __shared__ ushort_t Bs[4][64 * 32];

    const int K = D_MODEL;
    const int tid  = threadIdx.x;
    const int wave = tid >> 6, lane = tid & 63;
    const int quad = lane >> 4, l16 = lane & 15;
    // XCD swizzle: L%8 = XCD -> work w contiguous per XCD (768 = 8*96)
    const int L = blockIdx.x;
    const int wrk = (L & 7) * 96 + (L >> 3);
    const int rowBase = (wrk / 24) * 128, colBase = (wrk % 24) * 64;
    const int wm = (wave >> 1) * 64, wn = (wave & 1) * 32;

    f32x4 acc[4][2];
    const f32x4 zz = {0.f, 0.f, 0.f, 0.f};
#pragma unroll
    for (int i = 0; i < 4; i++)
#pragma unroll
        for (int j = 0; j < 2; j++) acc[i][j] = zz;

    const int sr = wave * 32 + (lane >> 2);
    const int sc = ((lane & 3) ^ ((lane >> 3) & 3)) * 8;
    const ushort_t* Ag0 = A + (size_t)(rowBase + sr) * K + sc;
    const ushort_t* Ag1 = A + (size_t)(rowBase + sr + 16) * K + sc;
    const int segA0 = (wave * 2 + 0) * 512, segA1 = (wave * 2 + 1) * 512;
    const int br = wave * 16 + (lane >> 2);
    const ushort_t* Bg0 = Bt + (size_t)(colBase + br) * K + sc;
    const int segB = wave * 512;

    const int fcol = (quad ^ ((l16 >> 1) & 3)) * 8;

    // prologue: stage slots 0 (k=0) and 1 (k=32)
    GLDS(Ag0, &As[0][segA0]);
    GLDS(Ag1, &As[0][segA1]);
    GLDS(Bg0, &Bs[0][segB]);
    GLDS(Ag0 + 32, &As[1][segA0]);
    GLDS(Ag1 + 32, &As[1][segA1]);
    GLDS(Bg0 + 32, &Bs[1][segB]);

#define QKV_COMPUTE(curslot) { \
        h16x8 af[4], bf[2]; \
        _Pragma("unroll") \
        for (int mt = 0; mt < 4; mt++) \
            af[mt] = *(const h16x8*)&As[curslot][(wm + mt * 16 + l16) * 32 + fcol]; \
        _Pragma("unroll") \
        for (int nt = 0; nt < 2; nt++) \
            bf[nt] = *(const h16x8*)&Bs[curslot][(wn + nt * 16 + l16) * 32 + fcol]; \
        _Pragma("unroll") \
        for (int mt = 0; mt < 4; mt++) \
            _Pragma("unroll") \
            for (int nt = 0; nt < 2; nt++) \
                acc[mt][nt] = MFMAH(af[mt], bf[nt], acc[mt][nt]); \
    }

    for (int k0 = 0; k0 < K; k0 += 64) {
        const int s0 = (k0 >> 5) & 3, s1 = (s0 + 1) & 3;
        const int s2 = (s0 + 2) & 3, s3 = (s0 + 3) & 3;
        __syncthreads();   // slots s0,s1 staged (issued last pair) now drained
        if (k0 + 64 < K) {
            GLDS(Ag0 + k0 + 64, &As[s2][segA0]);
            GLDS(Ag1 + k0 + 64, &As[s2][segA1]);
            GLDS(Bg0 + k0 + 64, &Bs[s2][segB]);
        }
        if (k0 + 96 < K) {
            GLDS(Ag0 + k0 + 96, &As[s3][segA0]);
            GLDS(Ag1 + k0 + 96, &As[s3][segA1]);
            GLDS(Bg0 + k0 + 96, &Bs[s3][segB]);
        }
        QKV_COMPUTE(s0);
        QKV_COMPUTE(s1);
    }
#undef QKV_COMPUTE

    if (colBase < 1024) {
        // ---- Q region: plain store to Qh (stride 1024)
#pragma unroll
        for (int mt = 0; mt < 4; mt++)
#pragma unroll
            for (int nt = 0; nt < 2; nt++) {
                const int row = rowBase + wm + mt * 16 + quad * 4;
                const int col = colBase + wn + nt * 16 + l16;
#pragma unroll
                for (int r = 0; r < 4; r++)
                    Qh[(size_t)(row + r) * D_MODEL + col] = f2h(acc[mt][nt][r]);
            }
    } else if (colBase < 1280) {
        // ---- K region: in-register rope (pair = acc[mt][0]/acc[mt][1])
        const int h = (colBase - 1024) >> 6;
        const int p = wn + l16;                 // [0,16) u [32,48)
        const int j = (p < 32) ? p : p - 16;    // [0,32)
#pragma unroll
        for (int mt = 0; mt < 4; mt++) {
            const int rowm = rowBase + wm + mt * 16 + quad * 4;
            const int bb = rowm >> 11, nb = rowm & (NN - 1);
            ushort_t* dstK = Kb + ((size_t)(bb * 4 + h) * NN) * 64;
#pragma unroll
            for (int r = 0; r < 4; r++) {
                const int n = nb + r;
                const float c = Cos[n * 32 + j], s = Sin[n * 32 + j];
                const float e = acc[mt][0][r], o = acc[mt][1][r];
                ushort_t* dk = dstK + (size_t)n * 64;
                dk[j]      = f2h(e * c - o * s);
                dk[j + 32] = f2h(e * s + o * c);
            }
        }
    } else {
        // ---- V region: transposed store to Vt (one uint2 per fragment)
        const int v0 = colBase - 1280;
#pragma unroll
        for (int mt = 0; mt < 4; mt++)
#pragma unroll
            for (int nt = 0; nt < 2; nt++) {
                const int d = v0 + wn + nt * 16 + l16;
                const int rowm = rowBase + wm + mt * 16 + quad * 4;
                const int bb = rowm >> 11, nb = rowm & (NN - 1);
                uint2 pk;
                pk.x = pk2h(acc[mt][nt][0], acc[mt][nt][1]);
                pk.y = pk2h(acc[mt][nt][2], acc[mt][nt][3]);
                *(uint2*)&Vt[((size_t)(bb * 256 + d)) * NN + nb] = pk;
            }
    }
}

// ---------------------------------------------------------------------------
// MFMA flash attention (round-14 structure verbatim, setprio REVERTED --
// r15 A/B showed it slightly negative for our barrier-synced waves).
// Q read from Qh (stride 1024), GLDS+swizzle dbuf staging, 1 barrier/tile,
// in-register K=16 PV, raw v_exp, MFMA denominator.
// ---------------------------------------------------------------------------
__global__ __launch_bounds__(256)
void attn_mfma(const ushort_t* __restrict__ Qh, const float* __restrict__ Cos,
               const float* __restrict__ Sin, const ushort_t* __restrict__ Kb,
               const ushort_t* __restrict__ Vt, ushort_t* __restrict__ Pnum,
               float* __restrict__ Pl)
{
    const int qt = blockIdx.x, h = blockIdx.y;
    const int b = blockIdx.z >> 1, chunk = blockIdx.z & 1;
    const int kvh = h >> 2;
    const int tid = threadIdx.x;
    const int wave = tid >> 6, lane = tid & 63;
    const int quad = lane >> 4, l16 = lane & 15;

    __shared__ ushort_t Ks[2][128][64];
    __shared__ ushort_t Vs[2][64][128];

    const int row0 = qt * 256 + wave * 64;
    const float SC = 0.125f * 1.44269504f;

    h16x8 qf[4][2];
#pragma unroll
    for (int mt = 0; mt < 4; mt++) {
        const int n = row0 + mt * 16 + l16;
        // pre-rope Q row: cols h*64 + [2j, 2j+1] for j = quad*8 + i
        const uint_t* pr =
            (const uint_t*)(Qh + (size_t)(b * NN + n) * D_MODEL + h * 64) + quad * 8;
        uint4 pa = *(const uint4*)pr;
        uint4 pc = *(const uint4*)(pr + 4);
        const uint_t pk[8] = {pa.x, pa.y, pa.z, pa.w, pc.x, pc.y, pc.z, pc.w};
        const float4 c0 = *(const float4*)&Cos[(size_t)n * 32 + quad * 8];
        const float4 c1 = *(const float4*)&Cos[(size_t)n * 32 + quad * 8 + 4];
        const float4 s0 = *(const float4*)&Sin[(size_t)n * 32 + quad * 8];
        const float4 s1 = *(const float4*)&Sin[(size_t)n * 32 + quad * 8 + 4];
        const float cc[8] = {c0.x, c0.y, c0.z, c0.w, c1.x, c1.y, c1.z, c1.w};
        const float ss[8] = {s0.x, s0.y, s0.z, s0.w, s1.x, s1.y, s1.z, s1.w};
#pragma unroll
        for (int i = 0; i < 8; i++) {
            const float e = h2f((ushort_t)pk[i]);
            const float o = h2f((ushort_t)(pk[i] >> 16));
            qf[mt][0][i] = (_Float16)((e * cc[i] - o * ss[i]) * SC);
            qf[mt][1][i] = (_Float16)((e * ss[i] + o * cc[i]) * SC);
        }
    }

    h16x4 ones;
#pragma unroll
    for (int i = 0; i < 4; i++) ones[i] = (_Float16)1.0f;

    const ushort_t* kbase = Kb + (size_t)(b * 4 + kvh) * NN * 64;
    const ushort_t* vbase = Vt + (size_t)(b * 256 + kvh * 64) * NN;
    const int key_lo = chunk * (NN / NSPLIT);          // 1024-key chunk
    const int rot = (qt + ((h & 3) << 2)) & (NTILE - 1);

    // staging lane constants (GLDS: dest = wave-uniform base + lane*16)
    const int krow = (wave << 3) + (lane >> 3);        // row within 32-row group
    const int kseg = (lane & 7) ^ (krow & 7);          // pre-swizzled global seg
    const ushort_t* kp_lane = kbase + (size_t)krow * 64 + kseg * 8;
    const int vrow = (wave << 2) + (lane >> 4);        // row within 16-row group
    const int vseg = (lane & 15) ^ (vrow & 7);
    const ushort_t* vp_lane = vbase + (size_t)vrow * NN + vseg * 8;

#define STAGE(key, bufidx) { \
        _Pragma("unroll") \
        for (int i = 0; i < 4; i++) { \
            GLDS(kp_lane + (size_t)((key) + i * 32) * 64, &Ks[bufidx][i * 32 + (wave << 3)][0]); \
            GLDS(vp_lane + (size_t)(i * 16) * NN + (key), &Vs[bufidx][i * 16 + (wave << 2)][0]); \
        } \
    }

    const f32x4 zz = {0.f, 0.f, 0.f, 0.f};
    f32x4 o[4][4];
#pragma unroll
    for (int mt = 0; mt < 4; mt++)
#pragma unroll
        for (int dt = 0; dt < 4; dt++) o[mt][dt] = zz;
    f32x4 lsum[4];
#pragma unroll
    for (int mt = 0; mt < 4; mt++) lsum[mt] = zz;

    // prologue: stage tile 0 into buf 0
    STAGE(key_lo + rot * KVBLK, 0);

    const int kswz = l16 & 7;

    for (int t = 0; t < NTILE; t++) {
        const int cur = t & 1, nxt = cur ^ 1;
        __syncthreads();   // drains GLDS for buf[cur]; prev compute (buf[nxt]) done
        if (t < NTILE - 1) {
            const int kn = key_lo + ((rot + t + 1) & (NTILE - 1)) * KVBLK;
            STAGE(kn, nxt);   // lands during compute below, drained next barrier
        }

        // ---- fused per-kt: S^T = K Q^T -> exp2 -> pack -> PV (K=16, P in regs)
#pragma unroll
        for (int kt = 0; kt < 8; kt++) {
            h16x8 kf0 = *(const h16x8*)&Ks[cur][kt * 16 + l16][(quad ^ kswz) << 3];
            h16x8 kf1 = *(const h16x8*)&Ks[cur][kt * 16 + l16][((4 + quad) ^ kswz) << 3];
            // V fragments: global col kt*16+quad*4 -> seg 2kt+(quad>>1), half quad&1
            h16x4 va[4];
#pragma unroll
            for (int dt = 0; dt < 4; dt++)
                va[dt] = *(const h16x4*)&Vs[cur][dt * 16 + l16]
                    [(((kt * 2 + (quad >> 1)) ^ kswz) << 3) + ((quad & 1) << 2)];

            uint2 pb[4];
#pragma unroll
            for (int mt = 0; mt < 4; mt++) {
                f32x4 st = MFMAH(kf0, qf[mt][0], zz);
                st = MFMAH(kf1, qf[mt][1], st);
                pb[mt].x = pk2h(EXP2(st[0]), EXP2(st[1]));
                pb[mt].y = pk2h(EXP2(st[2]), EXP2(st[3]));
            }
#pragma unroll
            for (int mt = 0; mt < 4; mt++) {
                const h16x4 pbv = *(const h16x4*)&pb[mt];
#pragma unroll
                for (int dt = 0; dt < 4; dt++)
                    o[mt][dt] = MFMA16(va[dt], pbv, o[mt][dt]);
                lsum[mt] = MFMA16(ones, pbv, lsum[mt]);
            }
        }
    }
#undef STAGE

    const size_t task0 = (size_t)(b * 16 + h) * NN + row0;
    ushort_t* np = Pnum + ((size_t)chunk * NTASK + task0) * 64;
#pragma unroll
    for (int mt = 0; mt < 4; mt++) {
        const float lt = lsum[mt][0];    // denom for q=l16 (rows identical)
        const float inv = 1.0f / lt;
#pragma unroll
        for (int dt = 0; dt < 4; dt++) {
            f32x4 v = o[mt][dt];
            uint2 pk;
            pk.x = pk2h(v[0] * inv, v[1] * inv);
            pk.y = pk2h(v[2] * inv, v[3] * inv);
            *(uint2*)&np[(size_t)(mt * 16 + l16) * 64 + dt * 16 + quad * 4] = pk;
        }
        if (quad == 0)
            Pl[(size_t)chunk * NTASK + task0 + mt * 16 + l16] = lt;
    }
}

// ---------------------------------------------------------------------------
// Split-K combine (2-way) + relayout to plain [row][D_MODEL] f16 matrix.
// ---------------------------------------------------------------------------
__global__ __launch_bounds__(256)
void combine_kernel(const ushort_t* __restrict__ Pnum, const float* __restrict__ Pl,
                    ushort_t* __restrict__ Ob)
{
    const uint_t i = blockIdx.x * 256 + threadIdx.x;   // 8-elem group, 524288 total
    const int row = i >> 7;            // 128 groups per 1024-col row
    const int g = i & 127;
    const int col0 = g * 8;
    const int h = col0 >> 6, d = col0 & 63;
    const int b = row >> 11, n = row & (NN - 1);
    const size_t task = ((size_t)(b * 16 + h) << 11) + n;

    float l[NSPLIT], tot = 0.f;
#pragma unroll
    for (int c = 0; c < NSPLIT; c++) { l[c] = Pl[(size_t)c * NTASK + task]; tot += l[c]; }
    const float inv = 1.f / tot;

    uint4 in[NSPLIT];
#pragma unroll
    for (int c = 0; c < NSPLIT; c++)
        in[c] = *(const uint4*)&Pnum[((size_t)c * NTASK + task) * 64 + d];

    uint4 out;
    uint_t* po = (uint_t*)&out;
#pragma unroll
    for (int j = 0; j < 4; j++) {
        float x = 0.f, y = 0.f;
#pragma unroll
        for (int c = 0; c < NSPLIT; c++) {
            const float w = l[c] * inv;
            fp16x2 u = *(const fp16x2*)&((const uint_t*)&in[c])[j];
            x += w * (float)u.x;
            y += w * (float)u.y;
        }
        po[j] = pk2h(x, y);
    }
    *(uint4*)&Ob[(size_t)row * D_MODEL + col0] = out;
}

// ---------------------------------------------------------------------------
// Wo GEMM: plain f16 GEMM (fp32 out), 128x64 tile, 4-slot ring + XCD-aware
// blockIdx swizzle (1D grid 512 = 8 XCDs x 64): per XCD, 4 Obuf A-panels
// (1MB) + full WoT (2MB) fit its L2.
// ---------------------------------------------------------------------------
__global__ __launch_bounds__(256)
void gemm_wo(const ushort_t* __restrict__ A, const ushort_t* __restrict__ Bt,
             float* __restrict__ C)
{
    __shared__ ushort_t As[4][128 * 32];
    __shared__ ushort_t Bs[4][64 * 32];

    const int tid  = threadIdx.x;
    const int wave = tid >> 6, lane = tid & 63;
    const int quad = lane >> 4, l16 = lane & 15;
    // XCD swizzle (512 = 8*64)
    const int L = blockIdx.x;
    const int wrk = (L & 7) * 64 + (L >> 3);
    const int rowBase = (wrk / 16) * 128, colBase = (wrk % 16) * 64;
    const int wm = (wave >> 1) * 64, wn = (wave & 1) * 32;

    f32x4 acc[4][2];
    const f32x4 zz = {0.f, 0.f, 0.f, 0.f};
#pragma unroll
    for (int i = 0; i < 4; i++)
#pragma unroll
        for (int j = 0; j < 2; j++) acc[i][j] = zz;

    const int sr = wave * 32 + (lane >> 2);
    const int sc = ((lane & 3) ^ ((lane >> 3) & 3)) * 8;
    const ushort_t* Ag0 = A + (size_t)(rowBase + sr) * D_MODEL + sc;
    const ushort_t* Ag1 = A + (size_t)(rowBase + sr + 16) * D_MODEL + sc;
    const int segA0 = (wave * 2 + 0) * 512, segA1 = (wave * 2 + 1) * 512;
    const int br = wave * 16 + (lane >> 2);
    const ushort_t* Bg0 = Bt + (size_t)(colBase + br) * D_MODEL + sc;
    const int segB = wave * 512;

    const int fcol = (quad ^ ((l16 >> 1) & 3)) * 8;

    GLDS(Ag0, &As[0][segA0]);
    GLDS(Ag1, &As[0][segA1]);
    GLDS(Bg0, &Bs[0][segB]);
    GLDS(Ag0 + 32, &As[1][segA0]);
    GLDS(Ag1 + 32, &As[1][segA1]);
    GLDS(Bg0 + 32, &Bs[1][segB]);

#define WO_COMPUTE(curslot) { \
        h16x8 af[4], bf[2]; \
        _Pragma("unroll") \
        for (int mt = 0; mt < 4; mt++) \
            af[mt] = *(const h16x8*)&As[curslot][(wm + mt * 16 + l16) * 32 + fcol]; \
        _Pragma("unroll") \
        for (int nt = 0; nt < 2; nt++) \
            bf[nt] = *(const h16x8*)&Bs[curslot][(wn + nt * 16 + l16) * 32 + fcol]; \
        _Pragma("unroll") \
        for (int mt = 0; mt < 4; mt++) \
            _Pragma("unroll") \
            for (int nt = 0; nt < 2; nt++) \
                acc[mt][nt] = MFMAH(af[mt], bf[nt], acc[mt][nt]); \
    }

    for (int k0 = 0; k0 < D_MODEL; k0 += 64) {
        const int s0 = (k0 >> 5) & 3, s1 = (s0 + 1) & 3;
        const int s2 = (s0 + 2) & 3, s3 = (s0 + 3) & 3;
        __syncthreads();
        if (k0 + 64 < D_MODEL) {
            GLDS(Ag0 + k0 + 64, &As[s2][segA0]);
            GLDS(Ag1 + k0 + 64, &As[s2][segA1]);
            GLDS(Bg0 + k0 + 64, &Bs[s2][segB]);
        }
        if (k0 + 96 < D_MODEL) {
            GLDS(Ag0 + k0 + 96, &As[s3][segA0]);
            GLDS(Ag1 + k0 + 96, &As[s3][segA1]);
            GLDS(Bg0 + k0 + 96, &Bs[s3][segB]);
        }
        WO_COMPUTE(s0);
        WO_COMPUTE(s1);
    }
#undef WO_COMPUTE

#pragma unroll
    for (int mt = 0; mt < 4; mt++)
#pragma unroll
        for (int nt = 0; nt < 2; nt++) {
            const int row = rowBase + wm + mt * 16 + quad * 4;
            const int col = colBase + wn + nt * 16 + l16;
#pragma unroll
            for (int r = 0; r < 4; r++)
                C[(size_t)(row + r) * D_MODEL + col] = acc[mt][nt][r];
        }
}

// ---------------------------------------------------------------------------
extern "C" void kernel_launch(void* const* d_in, const int* in_sizes, int n_in,
                              void* d_out, int out_size, void* d_ws, size_t ws_size,
                              hipStream_t stream)
{
    const float* x    = (const float*)d_in[0];
    const float* cosp = (const float*)d_in[1];
    const float* sinp = (const float*)d_in[2];
    const float* Wq   = (const float*)d_in[3];
    const float* Wk   = (const float*)d_in[4];
    const float* Wv   = (const float*)d_in[5];
    const float* Wo   = (const float*)d_in[6];

    char* w = (char*)d_ws;
    ushort_t* xb     = (ushort_t*)w;                       w += (size_t)MROWS * D_MODEL * 2;
    ushort_t* WqkvT  = (ushort_t*)w;                       w += (size_t)QKVN * D_MODEL * 2;
    ushort_t* WoT    = (ushort_t*)w;                       w += (size_t)D_MODEL * D_MODEL * 2;
    ushort_t* Qh     = (ushort_t*)w;                       w += (size_t)MROWS * D_MODEL * 2;
    ushort_t* Kbuf   = (ushort_t*)w;                       w += (size_t)MROWS * KVDIM * 2;
    ushort_t* Vt     = (ushort_t*)w;                       w += (size_t)MROWS * KVDIM * 2;
    ushort_t* Obuf   = (ushort_t*)w;                       w += (size_t)MROWS * D_MODEL * 2;
    ushort_t* Pnum   = (ushort_t*)w;                       w += (size_t)NSPLIT * NTASK * 64 * 2;
    float*    Pl     = (float*)w;

    // --- fused prep (cast + 4 transposes, K-weight rho-permute): 1 dispatch
    prep_kernel<<<6656, 256, 0, stream>>>(x, Wq, Wk, Wv, Wo, xb, WqkvT, WoT);

    // --- fused QKV projection + K-rope + V-transpose epilogue, XCD swizzle
    gemm_qkv<<<768, 256, 0, stream>>>(
        xb, WqkvT, cosp, sinp, Qh, Kbuf, Vt);

    // --- attention (split-K x2, GLDS+swizzle dbuf staging, no setprio)
    attn_mfma<<<dim3(NN / 256, NHEADS, BB * NSPLIT), 256, 0, stream>>>(
        Qh, cosp, sinp, Kbuf, Vt, Pnum, Pl);

    // --- 2-way split-K combine -> plain f16 matrix
    combine_kernel<<<(MROWS * D_MODEL / 8) / 256, 256, 0, stream>>>(
        Pnum, Pl, Obuf);

    // --- output projection (plain GEMM, fp32 out), 4-slot ring, XCD swizzle
    gemm_wo<<<512, 256, 0, stream>>>(
        Obuf, WoT, (float*)d_out);
}

// Round 17
// 180.224 us; speedup vs baseline: 1.0313x; 1.0005x over previous
//
#include <hip/hip_runtime.h>
#include <math.h>

#define D_MODEL 1024
#define NHEADS  16
#define NKV     4
#define HDIM    64
#define KVDIM   256
#define BB      2
#define NN      2048
#define MROWS   (BB*NN)        // 4096
#define QKVN    1536           // 1024 + 256 + 256
#define NTASK   (MROWS*NHEADS) // 65536
#define NSPLIT  2
#define KVBLK   128
#define NTILE   ((NN/NSPLIT)/KVBLK)   // 8

typedef unsigned short ushort_t;
typedef unsigned int uint_t;
typedef float    f32x4 __attribute__((ext_vector_type(4)));
typedef _Float16 h16x8 __attribute__((ext_vector_type(8)));
typedef _Float16 h16x4 __attribute__((ext_vector_type(4)));
typedef __fp16   fp16x2 __attribute__((ext_vector_type(2)));

#define MFMAH(A,B,C)  __builtin_amdgcn_mfma_f32_16x16x32_f16((A),(B),(C),0,0,0)
// NOTE spelling: carried-forward GCN-era intrinsic has NO underscore before f16
#define MFMA16(A,B,C) __builtin_amdgcn_mfma_f32_16x16x16f16((A),(B),(C),0,0,0)
// raw v_exp_f32 (1 instr) -- libm exp2f carries a ~6-instr denormal fixup
#define EXP2(x) __builtin_amdgcn_exp2f(x)

// async global->LDS, 16B per lane; LDS dest = wave-uniform base + lane*16
#define GLDS(gp, lp) __builtin_amdgcn_global_load_lds( \
    (const __attribute__((address_space(1))) void*)(gp), \
    (__attribute__((address_space(3))) void*)(lp), 16, 0, 0)

__device__ __forceinline__ ushort_t f2h(float f) {
    _Float16 h = (_Float16)f;
    return *(ushort_t*)&h;
}
__device__ __forceinline__ float h2f(ushort_t u) {
    return (float)(*(const _Float16*)&u);
}
// two fp32 -> packed f16x2, single v_cvt_pkrtz_f16_f32
__device__ __forceinline__ uint_t pk2h(float a, float b) {
    fp16x2 v = __builtin_amdgcn_cvt_pkrtz(a, b);
    return *(uint_t*)&v;
}

// ---------------------------------------------------------------------------
// Fused prep: cast x->f16 (blocks [0,4096)) + 4 weight transpose-casts
// (blocks [4096,6656)). K-weight columns are PERMUTED within each head:
// rho(2j) = p, rho(2j+1) = p+16 with p = (j<16)? j : j+16 -- so the rope
// pair (2j,2j+1) lands in the SAME LANE (nt=0/nt=1 registers) of the QKV
// GEMM epilogue, making K-rope lane-local there.
// ---------------------------------------------------------------------------
__global__ __launch_bounds__(256)
void prep_kernel(const float* __restrict__ x, const float* __restrict__ Wq,
                 const float* __restrict__ Wk, const float* __restrict__ Wv,
                 const float* __restrict__ Wo, ushort_t* __restrict__ xb,
                 ushort_t* __restrict__ WqkvT, ushort_t* __restrict__ WoT)
{
    __shared__ float T[32][33];
    int blk = blockIdx.x;
    if (blk < 4096) {                      // cast: 4096*256*4 = 4M elements
        const int i = blk * 256 + threadIdx.x;
        float4 v = ((const float4*)x)[i];
        uint2 o;
        o.x = pk2h(v.x, v.y);
        o.y = pk2h(v.z, v.w);
        ((uint2*)xb)[i] = o;
        return;
    }
    blk -= 4096;
    const float* src; ushort_t* dst; int N, bx, by; int kperm = 0;
    if (blk < 1024)      { src = Wq; dst = WqkvT;                            N = D_MODEL; bx = blk & 31; by = blk >> 5; }
    else if (blk < 1280) { blk -= 1024; src = Wk; dst = WqkvT + (size_t)1024 * D_MODEL; N = KVDIM; bx = blk & 7; by = blk >> 3; kperm = 1; }
    else if (blk < 1536) { blk -= 1280; src = Wv; dst = WqkvT + (size_t)1280 * D_MODEL; N = KVDIM; bx = blk & 7; by = blk >> 3; }
    else                 { blk -= 1536; src = Wo; dst = WoT;                 N = D_MODEL; bx = blk & 31; by = blk >> 5; }
    const int tx = threadIdx.x & 31, ty = threadIdx.x >> 5;
    const int n0 = bx * 32, k0 = by * 32;
#pragma unroll
    for (int i = 0; i < 4; i++)
        T[ty + i * 8][tx] = src[(size_t)(k0 + ty + i * 8) * N + n0 + tx];
    __syncthreads();
#pragma unroll
    for (int i = 0; i < 4; i++) {
        int c = n0 + ty + i * 8;
        if (kperm) {
            const int hd = c >> 6, ch = c & 63;
            const int j = ch >> 1, odd = ch & 1;
            const int p = ((j < 16) ? j : j + 16) + odd * 16;
            c = hd * 64 + p;
        }
        dst[(size_t)c * D_MODEL + k0 + tx] = f2h(T[tx][ty + i * 8]);
    }
}

// ---------------------------------------------------------------------------
// f16 MFMA GEMM for QKV, 128x64 tile, 4-slot LDS ring + XCD swizzle
// (round-16 proven config). Epilogue fusion: Q->Qh raw, K->rope in-register
// (rho-permuted weights), V->transposed Vt.
// ---------------------------------------------------------------------------
__global__ __launch_bounds__(256)
void gemm_qkv(const ushort_t* __restrict__ A, const ushort_t* __restrict__ Bt,
              const float* __restrict__ Cos, const float* __restrict__ Sin,
              ushort_t* __restrict__ Qh, ushort_t* __restrict__ Kb,
              ushort_t* __restrict__ Vt)
{
    __shared__ ushort_t As[4][128 * 32];
    __shared__ ushort_t Bs[4][64 * 32];

    const int K = D_MODEL;
    const int tid  = threadIdx.x;
    const int wave = tid >> 6, lane = tid & 63;
    const int quad = lane >> 4, l16 = lane & 15;
    // XCD swizzle: L%8 = XCD -> work w contiguous per XCD (768 = 8*96)
    const int L = blockIdx.x;
    const int wrk = (L & 7) * 96 + (L >> 3);
    const int rowBase = (wrk / 24) * 128, colBase = (wrk % 24) * 64;
    const int wm = (wave >> 1) * 64, wn = (wave & 1) * 32;

    f32x4 acc[4][2];
    const f32x4 zz = {0.f, 0.f, 0.f, 0.f};
#pragma unroll
    for (int i = 0; i < 4; i++)
#pragma unroll
        for (int j = 0; j < 2; j++) acc[i][j] = zz;

    const int sr = wave * 32 + (lane >> 2);
    const int sc = ((lane & 3) ^ ((lane >> 3) & 3)) * 8;
    const ushort_t* Ag0 = A + (size_t)(rowBase + sr) * K + sc;
    const ushort_t* Ag1 = A + (size_t)(rowBase + sr + 16) * K + sc;
    const int segA0 = (wave * 2 + 0) * 512, segA1 = (wave * 2 + 1) * 512;
    const int br = wave * 16 + (lane >> 2);
    const ushort_t* Bg0 = Bt + (size_t)(colBase + br) * K + sc;
    const int segB = wave * 512;

    const int fcol = (quad ^ ((l16 >> 1) & 3)) * 8;

    // prologue: stage slots 0 (k=0) and 1 (k=32)
    GLDS(Ag0, &As[0][segA0]);
    GLDS(Ag1, &As[0][segA1]);
    GLDS(Bg0, &Bs[0][segB]);
    GLDS(Ag0 + 32, &As[1][segA0]);
    GLDS(Ag1 + 32, &As[1][segA1]);
    GLDS(Bg0 + 32, &Bs[1][segB]);

#define QKV_COMPUTE(curslot) { \
        h16x8 af[4], bf[2]; \
        _Pragma("unroll") \
        for (int mt = 0; mt < 4; mt++) \
            af[mt] = *(const h16x8*)&As[curslot][(wm + mt * 16 + l16) * 32 + fcol]; \
        _Pragma("unroll") \
        for (int nt = 0; nt < 2; nt++) \
            bf[nt] = *(const h16x8*)&Bs[curslot][(wn + nt * 16 + l16) * 32 + fcol]; \
        _Pragma("unroll") \
        for (int mt = 0; mt < 4; mt++) \
            _Pragma("unroll") \
            for (int nt = 0; nt < 2; nt++) \
                acc[mt][nt] = MFMAH(af[mt], bf[nt], acc[mt][nt]); \
    }

    for (int k0 = 0; k0 < K; k0 += 64) {
        const int s0 = (k0 >> 5) & 3, s1 = (s0 + 1) & 3;
        const int s2 = (s0 + 2) & 3, s3 = (s0 + 3) & 3;
        __syncthreads();   // slots s0,s1 staged (issued last pair) now drained
        if (k0 + 64 < K) {
            GLDS(Ag0 + k0 + 64, &As[s2][segA0]);
            GLDS(Ag1 + k0 + 64, &As[s2][segA1]);
            GLDS(Bg0 + k0 + 64, &Bs[s2][segB]);
        }
        if (k0 + 96 < K) {
            GLDS(Ag0 + k0 + 96, &As[s3][segA0]);
            GLDS(Ag1 + k0 + 96, &As[s3][segA1]);
            GLDS(Bg0 + k0 + 96, &Bs[s3][segB]);
        }
        QKV_COMPUTE(s0);
        QKV_COMPUTE(s1);
    }
#undef QKV_COMPUTE

    if (colBase < 1024) {
        // ---- Q region: plain store to Qh (stride 1024)
#pragma unroll
        for (int mt = 0; mt < 4; mt++)
#pragma unroll
            for (int nt = 0; nt < 2; nt++) {
                const int row = rowBase + wm + mt * 16 + quad * 4;
                const int col = colBase + wn + nt * 16 + l16;
#pragma unroll
                for (int r = 0; r < 4; r++)
                    Qh[(size_t)(row + r) * D_MODEL + col] = f2h(acc[mt][nt][r]);
            }
    } else if (colBase < 1280) {
        // ---- K region: in-register rope (pair = acc[mt][0]/acc[mt][1])
        const int h = (colBase - 1024) >> 6;
        const int p = wn + l16;                 // [0,16) u [32,48)
        const int j = (p < 32) ? p : p - 16;    // [0,32)
#pragma unroll
        for (int mt = 0; mt < 4; mt++) {
            const int rowm = rowBase + wm + mt * 16 + quad * 4;
            const int bb = rowm >> 11, nb = rowm & (NN - 1);
            ushort_t* dstK = Kb + ((size_t)(bb * 4 + h) * NN) * 64;
#pragma unroll
            for (int r = 0; r < 4; r++) {
                const int n = nb + r;
                const float c = Cos[n * 32 + j], s = Sin[n * 32 + j];
                const float e = acc[mt][0][r], o = acc[mt][1][r];
                ushort_t* dk = dstK + (size_t)n * 64;
                dk[j]      = f2h(e * c - o * s);
                dk[j + 32] = f2h(e * s + o * c);
            }
        }
    } else {
        // ---- V region: transposed store to Vt (one uint2 per fragment)
        const int v0 = colBase - 1280;
#pragma unroll
        for (int mt = 0; mt < 4; mt++)
#pragma unroll
            for (int nt = 0; nt < 2; nt++) {
                const int d = v0 + wn + nt * 16 + l16;
                const int rowm = rowBase + wm + mt * 16 + quad * 4;
                const int bb = rowm >> 11, nb = rowm & (NN - 1);
                uint2 pk;
                pk.x = pk2h(acc[mt][nt][0], acc[mt][nt][1]);
                pk.y = pk2h(acc[mt][nt][2], acc[mt][nt][3]);
                *(uint2*)&Vt[((size_t)(bb * 256 + d)) * NN + nb] = pk;
            }
    }
}

// ---------------------------------------------------------------------------
// MFMA flash attention. Round-29: kt-PAIR ILP restructure -- process two
// kt's per iteration: issue both LDS fragment reads + all 8 independent QK
// MFMA chains first, then all exps, then both PV groups. Doubles the
// independent work available at every stall point (dependent MFMAH pair,
// exp latency) -- targeted at the ~29% stall measured at 2 waves/SIMD
// where TLP can't hide chain latency. Everything else = r16 winner.
// ---------------------------------------------------------------------------
__global__ __launch_bounds__(256)
void attn_mfma(const ushort_t* __restrict__ Qh, const float* __restrict__ Cos,
               const float* __restrict__ Sin, const ushort_t* __restrict__ Kb,
               const ushort_t* __restrict__ Vt, ushort_t* __restrict__ Pnum,
               float* __restrict__ Pl)
{
    const int qt = blockIdx.x, h = blockIdx.y;
    const int b = blockIdx.z >> 1, chunk = blockIdx.z & 1;
    const int kvh = h >> 2;
    const int tid = threadIdx.x;
    const int wave = tid >> 6, lane = tid & 63;
    const int quad = lane >> 4, l16 = lane & 15;

    __shared__ ushort_t Ks[2][128][64];
    __shared__ ushort_t Vs[2][64][128];

    const int row0 = qt * 256 + wave * 64;
    const float SC = 0.125f * 1.44269504f;

    h16x8 qf[4][2];
#pragma unroll
    for (int mt = 0; mt < 4; mt++) {
        const int n = row0 + mt * 16 + l16;
        // pre-rope Q row: cols h*64 + [2j, 2j+1] for j = quad*8 + i
        const uint_t* pr =
            (const uint_t*)(Qh + (size_t)(b * NN + n) * D_MODEL + h * 64) + quad * 8;
        uint4 pa = *(const uint4*)pr;
        uint4 pc = *(const uint4*)(pr + 4);
        const uint_t pk[8] = {pa.x, pa.y, pa.z, pa.w, pc.x, pc.y, pc.z, pc.w};
        const float4 c0 = *(const float4*)&Cos[(size_t)n * 32 + quad * 8];
        const float4 c1 = *(const float4*)&Cos[(size_t)n * 32 + quad * 8 + 4];
        const float4 s0 = *(const float4*)&Sin[(size_t)n * 32 + quad * 8];
        const float4 s1 = *(const float4*)&Sin[(size_t)n * 32 + quad * 8 + 4];
        const float cc[8] = {c0.x, c0.y, c0.z, c0.w, c1.x, c1.y, c1.z, c1.w};
        const float ss[8] = {s0.x, s0.y, s0.z, s0.w, s1.x, s1.y, s1.z, s1.w};
#pragma unroll
        for (int i = 0; i < 8; i++) {
            const float e = h2f((ushort_t)pk[i]);
            const float o = h2f((ushort_t)(pk[i] >> 16));
            qf[mt][0][i] = (_Float16)((e * cc[i] - o * ss[i]) * SC);
            qf[mt][1][i] = (_Float16)((e * ss[i] + o * cc[i]) * SC);
        }
    }

    h16x4 ones;
#pragma unroll
    for (int i = 0; i < 4; i++) ones[i] = (_Float16)1.0f;

    const ushort_t* kbase = Kb + (size_t)(b * 4 + kvh) * NN * 64;
    const ushort_t* vbase = Vt + (size_t)(b * 256 + kvh * 64) * NN;
    const int key_lo = chunk * (NN / NSPLIT);          // 1024-key chunk
    const int rot = (qt + ((h & 3) << 2)) & (NTILE - 1);

    // staging lane constants (GLDS: dest = wave-uniform base + lane*16)
    const int krow = (wave << 3) + (lane >> 3);        // row within 32-row group
    const int kseg = (lane & 7) ^ (krow & 7);          // pre-swizzled global seg
    const ushort_t* kp_lane = kbase + (size_t)krow * 64 + kseg * 8;
    const int vrow = (wave << 2) + (lane >> 4);        // row within 16-row group
    const int vseg = (lane & 15) ^ (vrow & 7);
    const ushort_t* vp_lane = vbase + (size_t)vrow * NN + vseg * 8;

#define STAGE(key, bufidx) { \
        _Pragma("unroll") \
        for (int i = 0; i < 4; i++) { \
            GLDS(kp_lane + (size_t)((key) + i * 32) * 64, &Ks[bufidx][i * 32 + (wave << 3)][0]); \
            GLDS(vp_lane + (size_t)(i * 16) * NN + (key), &Vs[bufidx][i * 16 + (wave << 2)][0]); \
        } \
    }

    const f32x4 zz = {0.f, 0.f, 0.f, 0.f};
    f32x4 o[4][4];
#pragma unroll
    for (int mt = 0; mt < 4; mt++)
#pragma unroll
        for (int dt = 0; dt < 4; dt++) o[mt][dt] = zz;
    f32x4 lsum[4];
#pragma unroll
    for (int mt = 0; mt < 4; mt++) lsum[mt] = zz;

    // prologue: stage tile 0 into buf 0
    STAGE(key_lo + rot * KVBLK, 0);

    const int kswz = l16 & 7;

    for (int t = 0; t < NTILE; t++) {
        const int cur = t & 1, nxt = cur ^ 1;
        __syncthreads();   // drains GLDS for buf[cur]; prev compute (buf[nxt]) done
        if (t < NTILE - 1) {
            const int kn = key_lo + ((rot + t + 1) & (NTILE - 1)) * KVBLK;
            STAGE(kn, nxt);   // lands during compute below, drained next barrier
        }

        // ---- kt-PAIR pipeline: QK x2 -> exp x2 -> PV x2
#pragma unroll
        for (int kp = 0; kp < 4; kp++) {
            const int ka = kp * 2, kb2 = kp * 2 + 1;
            // fragment reads for both kts (issued together; one lgkm window)
            h16x8 kf0a = *(const h16x8*)&Ks[cur][ka * 16 + l16][(quad ^ kswz) << 3];
            h16x8 kf1a = *(const h16x8*)&Ks[cur][ka * 16 + l16][((4 + quad) ^ kswz) << 3];
            h16x8 kf0b = *(const h16x8*)&Ks[cur][kb2 * 16 + l16][(quad ^ kswz) << 3];
            h16x8 kf1b = *(const h16x8*)&Ks[cur][kb2 * 16 + l16][((4 + quad) ^ kswz) << 3];
            h16x4 vaa[4], vab[4];
#pragma unroll
            for (int dt = 0; dt < 4; dt++) {
                vaa[dt] = *(const h16x4*)&Vs[cur][dt * 16 + l16]
                    [(((ka * 2 + (quad >> 1)) ^ kswz) << 3) + ((quad & 1) << 2)];
                vab[dt] = *(const h16x4*)&Vs[cur][dt * 16 + l16]
                    [(((kb2 * 2 + (quad >> 1)) ^ kswz) << 3) + ((quad & 1) << 2)];
            }

            // QK for both kts: 8 independent MFMA chains
            f32x4 sta[4], stb[4];
#pragma unroll
            for (int mt = 0; mt < 4; mt++) {
                sta[mt] = MFMAH(kf0a, qf[mt][0], zz);
                stb[mt] = MFMAH(kf0b, qf[mt][0], zz);
            }
#pragma unroll
            for (int mt = 0; mt < 4; mt++) {
                sta[mt] = MFMAH(kf1a, qf[mt][1], sta[mt]);
                stb[mt] = MFMAH(kf1b, qf[mt][1], stb[mt]);
            }

            // exp + pack for both
            uint2 pba[4], pbb[4];
#pragma unroll
            for (int mt = 0; mt < 4; mt++) {
                pba[mt].x = pk2h(EXP2(sta[mt][0]), EXP2(sta[mt][1]));
                pba[mt].y = pk2h(EXP2(sta[mt][2]), EXP2(sta[mt][3]));
                pbb[mt].x = pk2h(EXP2(stb[mt][0]), EXP2(stb[mt][1]));
                pbb[mt].y = pk2h(EXP2(stb[mt][2]), EXP2(stb[mt][3]));
            }

            // PV for both kts
#pragma unroll
            for (int mt = 0; mt < 4; mt++) {
                const h16x4 pva = *(const h16x4*)&pba[mt];
                const h16x4 pvb = *(const h16x4*)&pbb[mt];
#pragma unroll
                for (int dt = 0; dt < 4; dt++) {
                    o[mt][dt] = MFMA16(vaa[dt], pva, o[mt][dt]);
                    o[mt][dt] = MFMA16(vab[dt], pvb, o[mt][dt]);
                }
                lsum[mt] = MFMA16(ones, pva, lsum[mt]);
                lsum[mt] = MFMA16(ones, pvb, lsum[mt]);
            }
        }
    }
#undef STAGE

    const size_t task0 = (size_t)(b * 16 + h) * NN + row0;
    ushort_t* np = Pnum + ((size_t)chunk * NTASK + task0) * 64;
#pragma unroll
    for (int mt = 0; mt < 4; mt++) {
        const float lt = lsum[mt][0];    // denom for q=l16 (rows identical)
        const float inv = 1.0f / lt;
#pragma unroll
        for (int dt = 0; dt < 4; dt++) {
            f32x4 v = o[mt][dt];
            uint2 pk;
            pk.x = pk2h(v[0] * inv, v[1] * inv);
            pk.y = pk2h(v[2] * inv, v[3] * inv);
            *(uint2*)&np[(size_t)(mt * 16 + l16) * 64 + dt * 16 + quad * 4] = pk;
        }
        if (quad == 0)
            Pl[(size_t)chunk * NTASK + task0 + mt * 16 + l16] = lt;
    }
}

// ---------------------------------------------------------------------------
// Split-K combine (2-way) + relayout to plain [row][D_MODEL] f16 matrix.
// ---------------------------------------------------------------------------
__global__ __launch_bounds__(256)
void combine_kernel(const ushort_t* __restrict__ Pnum, const float* __restrict__ Pl,
                    ushort_t* __restrict__ Ob)
{
    const uint_t i = blockIdx.x * 256 + threadIdx.x;   // 8-elem group, 524288 total
    const int row = i >> 7;            // 128 groups per 1024-col row
    const int g = i & 127;
    const int col0 = g * 8;
    const int h = col0 >> 6, d = col0 & 63;
    const int b = row >> 11, n = row & (NN - 1);
    const size_t task = ((size_t)(b * 16 + h) << 11) + n;

    float l[NSPLIT], tot = 0.f;
#pragma unroll
    for (int c = 0; c < NSPLIT; c++) { l[c] = Pl[(size_t)c * NTASK + task]; tot += l[c]; }
    const float inv = 1.f / tot;

    uint4 in[NSPLIT];
#pragma unroll
    for (int c = 0; c < NSPLIT; c++)
        in[c] = *(const uint4*)&Pnum[((size_t)c * NTASK + task) * 64 + d];

    uint4 out;
    uint_t* po = (uint_t*)&out;
#pragma unroll
    for (int j = 0; j < 4; j++) {
        float x = 0.f, y = 0.f;
#pragma unroll
        for (int c = 0; c < NSPLIT; c++) {
            const float w = l[c] * inv;
            fp16x2 u = *(const fp16x2*)&((const uint_t*)&in[c])[j];
            x += w * (float)u.x;
            y += w * (float)u.y;
        }
        po[j] = pk2h(x, y);
    }
    *(uint4*)&Ob[(size_t)row * D_MODEL + col0] = out;
}

// ---------------------------------------------------------------------------
// Wo GEMM: plain f16 GEMM (fp32 out), 128x64 tile, 4-slot ring + XCD-aware
// blockIdx swizzle (round-16 proven config).
// ---------------------------------------------------------------------------
__global__ __launch_bounds__(256)
void gemm_wo(const ushort_t* __restrict__ A, const ushort_t* __restrict__ Bt,
             float* __restrict__ C)
{
    __shared__ ushort_t As[4][128 * 32];
    __shared__ ushort_t Bs[4][64 * 32];

    const int tid  = threadIdx.x;
    const int wave = tid >> 6, lane = tid & 63;
    const int quad = lane >> 4, l16 = lane & 15;
    // XCD swizzle (512 = 8*64)
    const int L = blockIdx.x;
    const int wrk = (L & 7) * 64 + (L >> 3);
    const int rowBase = (wrk / 16) * 128, colBase = (wrk % 16) * 64;
    const int wm = (wave >> 1) * 64, wn = (wave & 1) * 32;

    f32x4 acc[4][2];
    const f32x4 zz = {0.f, 0.f, 0.f, 0.f};
#pragma unroll
    for (int i = 0; i < 4; i++)
#pragma unroll
        for (int j = 0; j < 2; j++) acc[i][j] = zz;

    const int sr = wave * 32 + (lane >> 2);
    const int sc = ((lane & 3) ^ ((lane >> 3) & 3)) * 8;
    const ushort_t* Ag0 = A + (size_t)(rowBase + sr) * D_MODEL + sc;
    const ushort_t* Ag1 = A + (size_t)(rowBase + sr + 16) * D_MODEL + sc;
    const int segA0 = (wave * 2 + 0) * 512, segA1 = (wave * 2 + 1) * 512;
    const int br = wave * 16 + (lane >> 2);
    const ushort_t* Bg0 = Bt + (size_t)(colBase + br) * D_MODEL + sc;
    const int segB = wave * 512;

    const int fcol = (quad ^ ((l16 >> 1) & 3)) * 8;

    GLDS(Ag0, &As[0][segA0]);
    GLDS(Ag1, &As[0][segA1]);
    GLDS(Bg0, &Bs[0][segB]);
    GLDS(Ag0 + 32, &As[1][segA0]);
    GLDS(Ag1 + 32, &As[1][segA1]);
    GLDS(Bg0 + 32, &Bs[1][segB]);

#define WO_COMPUTE(curslot) { \
        h16x8 af[4], bf[2]; \
        _Pragma("unroll") \
        for (int mt = 0; mt < 4; mt++) \
            af[mt] = *(const h16x8*)&As[curslot][(wm + mt * 16 + l16) * 32 + fcol]; \
        _Pragma("unroll") \
        for (int nt = 0; nt < 2; nt++) \
            bf[nt] = *(const h16x8*)&Bs[curslot][(wn + nt * 16 + l16) * 32 + fcol]; \
        _Pragma("unroll") \
        for (int mt = 0; mt < 4; mt++) \
            _Pragma("unroll") \
            for (int nt = 0; nt < 2; nt++) \
                acc[mt][nt] = MFMAH(af[mt], bf[nt], acc[mt][nt]); \
    }

    for (int k0 = 0; k0 < D_MODEL; k0 += 64) {
        const int s0 = (k0 >> 5) & 3, s1 = (s0 + 1) & 3;
        const int s2 = (s0 + 2) & 3, s3 = (s0 + 3) & 3;
        __syncthreads();
        if (k0 + 64 < D_MODEL) {
            GLDS(Ag0 + k0 + 64, &As[s2][segA0]);
            GLDS(Ag1 + k0 + 64, &As[s2][segA1]);
            GLDS(Bg0 + k0 + 64, &Bs[s2][segB]);
        }
        if (k0 + 96 < D_MODEL) {
            GLDS(Ag0 + k0 + 96, &As[s3][segA0]);
            GLDS(Ag1 + k0 + 96, &As[s3][segA1]);
            GLDS(Bg0 + k0 + 96, &Bs[s3][segB]);
        }
        WO_COMPUTE(s0);
        WO_COMPUTE(s1);
    }
#undef WO_COMPUTE

#pragma unroll
    for (int mt = 0; mt < 4; mt++)
#pragma unroll
        for (int nt = 0; nt < 2; nt++) {
            const int row = rowBase + wm + mt * 16 + quad * 4;
            const int col = colBase + wn + nt * 16 + l16;
#pragma unroll
            for (int r = 0; r < 4; r++)
                C[(size_t)(row + r) * D_MODEL + col] = acc[mt][nt][r];
        }
}

// ---------------------------------------------------------------------------
extern "C" void kernel_launch(void* const* d_in, const int* in_sizes, int n_in,
                              void* d_out, int out_size, void* d_ws, size_t ws_size,
                              hipStream_t stream)
{
    const float* x    = (const float*)d_in[0];
    const float* cosp = (const float*)d_in[1];
    const float* sinp = (const float*)d_in[2];
    const float* Wq   = (const float*)d_in[3];
    const float* Wk   = (const float*)d_in[4];
    const float* Wv   = (const float*)d_in[5];
    const float* Wo   = (const float*)d_in[6];

    char* w = (char*)d_ws;
    ushort_t* xb     = (ushort_t*)w;                       w += (size_t)MROWS * D_MODEL * 2;
    ushort_t* WqkvT  = (ushort_t*)w;                       w += (size_t)QKVN * D_MODEL * 2;
    ushort_t* WoT    = (ushort_t*)w;                       w += (size_t)D_MODEL * D_MODEL * 2;
    ushort_t* Qh     = (ushort_t*)w;                       w += (size_t)MROWS * D_MODEL * 2;
    ushort_t* Kbuf   = (ushort_t*)w;                       w += (size_t)MROWS * KVDIM * 2;
    ushort_t* Vt     = (ushort_t*)w;                       w += (size_t)MROWS * KVDIM * 2;
    ushort_t* Obuf   = (ushort_t*)w;                       w += (size_t)MROWS * D_MODEL * 2;
    ushort_t* Pnum   = (ushort_t*)w;                       w += (size_t)NSPLIT * NTASK * 64 * 2;
    float*    Pl     = (float*)w;

    // --- fused prep (cast + 4 transposes, K-weight rho-permute): 1 dispatch
    prep_kernel<<<6656, 256, 0, stream>>>(x, Wq, Wk, Wv, Wo, xb, WqkvT, WoT);

    // --- fused QKV projection + K-rope + V-transpose epilogue, XCD swizzle
    gemm_qkv<<<768, 256, 0, stream>>>(
        xb, WqkvT, cosp, sinp, Qh, Kbuf, Vt);

    // --- attention (split-K x2, GLDS+swizzle dbuf staging, kt-pair ILP)
    attn_mfma<<<dim3(NN / 256, NHEADS, BB * NSPLIT), 256, 0, stream>>>(
        Qh, cosp, sinp, Kbuf, Vt, Pnum, Pl);

    // --- 2-way split-K combine -> plain f16 matrix
    combine_kernel<<<(MROWS * D_MODEL / 8) / 256, 256, 0, stream>>>(
        Pnum, Pl, Obuf);

    // --- output projection (plain GEMM, fp32 out), 4-slot ring, XCD swizzle
    gemm_wo<<<512, 256, 0, stream>>>(
        Obuf, WoT, (float*)d_out);
}

// Round 19
// 178.862 us; speedup vs baseline: 1.0392x; 1.0076x over previous
//
#include <hip/hip_runtime.h>
#include <math.h>

#define D_MODEL 1024
#define NHEADS  16
#define NKV     4
#define HDIM    64
#define KVDIM   256
#define BB      2
#define NN      2048
#define MROWS   (BB*NN)        // 4096
#define QKVN    1536           // 1024 + 256 + 256
#define NTASK   (MROWS*NHEADS) // 65536
#define NSPLIT  2
#define KVBLK   128
#define NTILE   ((NN/NSPLIT)/KVBLK)   // 8

typedef unsigned short ushort_t;
typedef unsigned int uint_t;
typedef float    f32x4 __attribute__((ext_vector_type(4)));
typedef _Float16 h16x8 __attribute__((ext_vector_type(8)));
typedef _Float16 h16x4 __attribute__((ext_vector_type(4)));
typedef __fp16   fp16x2 __attribute__((ext_vector_type(2)));

#define MFMAH(A,B,C)  __builtin_amdgcn_mfma_f32_16x16x32_f16((A),(B),(C),0,0,0)
// NOTE spelling: carried-forward GCN-era intrinsic has NO underscore before f16
#define MFMA16(A,B,C) __builtin_amdgcn_mfma_f32_16x16x16f16((A),(B),(C),0,0,0)
// raw v_exp_f32 (1 instr) -- libm exp2f carries a ~6-instr denormal fixup
#define EXP2(x) __builtin_amdgcn_exp2f(x)

// async global->LDS, 16B per lane; LDS dest = wave-uniform base + lane*16
#define GLDS(gp, lp) __builtin_amdgcn_global_load_lds( \
    (const __attribute__((address_space(1))) void*)(gp), \
    (__attribute__((address_space(3))) void*)(lp), 16, 0, 0)

__device__ __forceinline__ ushort_t f2h(float f) {
    _Float16 h = (_Float16)f;
    return *(ushort_t*)&h;
}
__device__ __forceinline__ float h2f(ushort_t u) {
    return (float)(*(const _Float16*)&u);
}
// two fp32 -> packed f16x2, single v_cvt_pkrtz_f16_f32
__device__ __forceinline__ uint_t pk2h(float a, float b) {
    fp16x2 v = __builtin_amdgcn_cvt_pkrtz(a, b);
    return *(uint_t*)&v;
}

// ---------------------------------------------------------------------------
// Fused prep: cast x->f16 (blocks [0,4096)) + 4 weight transpose-casts
// (blocks [4096,6656)). K-weight columns are PERMUTED within each head:
// rho(2j) = p, rho(2j+1) = p+16 with p = (j<16)? j : j+16 -- so the rope
// pair (2j,2j+1) lands in the SAME LANE (nt=0/nt=1 registers) of the QKV
// GEMM epilogue, making K-rope lane-local there.
// ---------------------------------------------------------------------------
__global__ __launch_bounds__(256)
void prep_kernel(const float* __restrict__ x, const float* __restrict__ Wq,
                 const float* __restrict__ Wk, const float* __restrict__ Wv,
                 const float* __restrict__ Wo, ushort_t* __restrict__ xb,
                 ushort_t* __restrict__ WqkvT, ushort_t* __restrict__ WoT)
{
    __shared__ float T[32][33];
    int blk = blockIdx.x;
    if (blk < 4096) {                      // cast: 4096*256*4 = 4M elements
        const int i = blk * 256 + threadIdx.x;
        float4 v = ((const float4*)x)[i];
        uint2 o;
        o.x = pk2h(v.x, v.y);
        o.y = pk2h(v.z, v.w);
        ((uint2*)xb)[i] = o;
        return;
    }
    blk -= 4096;
    const float* src; ushort_t* dst; int N, bx, by; int kperm = 0;
    if (blk < 1024)      { src = Wq; dst = WqkvT;                            N = D_MODEL; bx = blk & 31; by = blk >> 5; }
    else if (blk < 1280) { blk -= 1024; src = Wk; dst = WqkvT + (size_t)1024 * D_MODEL; N = KVDIM; bx = blk & 7; by = blk >> 3; kperm = 1; }
    else if (blk < 1536) { blk -= 1280; src = Wv; dst = WqkvT + (size_t)1280 * D_MODEL; N = KVDIM; bx = blk & 7; by = blk >> 3; }
    else                 { blk -= 1536; src = Wo; dst = WoT;                 N = D_MODEL; bx = blk & 31; by = blk >> 5; }
    const int tx = threadIdx.x & 31, ty = threadIdx.x >> 5;
    const int n0 = bx * 32, k0 = by * 32;
#pragma unroll
    for (int i = 0; i < 4; i++)
        T[ty + i * 8][tx] = src[(size_t)(k0 + ty + i * 8) * N + n0 + tx];
    __syncthreads();
#pragma unroll
    for (int i = 0; i < 4; i++) {
        int c = n0 + ty + i * 8;
        if (kperm) {
            const int hd = c >> 6, ch = c & 63;
            const int j = ch >> 1, odd = ch & 1;
            const int p = ((j < 16) ? j : j + 16) + odd * 16;
            c = hd * 64 + p;
        }
        dst[(size_t)c * D_MODEL + k0 + tx] = f2h(T[tx][ty + i * 8]);
    }
}

// ---------------------------------------------------------------------------
// f16 MFMA GEMM for QKV, 128x64 tile, 4-slot LDS ring + XCD swizzle
// (round-16 proven config). Epilogue fusion: Q->Qh raw, K->rope in-register
// (rho-permuted weights), V->transposed Vt.
// ---------------------------------------------------------------------------
__global__ __launch_bounds__(256)
void gemm_qkv(const ushort_t* __restrict__ A, const ushort_t* __restrict__ Bt,
              const float* __restrict__ Cos, const float* __restrict__ Sin,
              ushort_t* __restrict__ Qh, ushort_t* __restrict__ Kb,
              ushort_t* __restrict__ Vt)
{
    __shared__ ushort_t As[4][128 * 32];
    __shared__ ushort_t Bs[4][64 * 32];

    const int K = D_MODEL;
    const int tid  = threadIdx.x;
    const int wave = tid >> 6, lane = tid & 63;
    const int quad = lane >> 4, l16 = lane & 15;
    // XCD swizzle: L%8 = XCD -> work w contiguous per XCD (768 = 8*96)
    const int L = blockIdx.x;
    const int wrk = (L & 7) * 96 + (L >> 3);
    const int rowBase = (wrk / 24) * 128, colBase = (wrk % 24) * 64;
    const int wm = (wave >> 1) * 64, wn = (wave & 1) * 32;

    f32x4 acc[4][2];
    const f32x4 zz = {0.f, 0.f, 0.f, 0.f};
#pragma unroll
    for (int i = 0; i < 4; i++)
#pragma unroll
        for (int j = 0; j < 2; j++) acc[i][j] = zz;

    const int sr = wave * 32 + (lane >> 2);
    const int sc = ((lane & 3) ^ ((lane >> 3) & 3)) * 8;
    const ushort_t* Ag0 = A + (size_t)(rowBase + sr) * K + sc;
    const ushort_t* Ag1 = A + (size_t)(rowBase + sr + 16) * K + sc;
    const int segA0 = (wave * 2 + 0) * 512, segA1 = (wave * 2 + 1) * 512;
    const int br = wave * 16 + (lane >> 2);
    const ushort_t* Bg0 = Bt + (size_t)(colBase + br) * K + sc;
    const int segB = wave * 512;

    const int fcol = (quad ^ ((l16 >> 1) & 3)) * 8;

    // prologue: stage slots 0 (k=0) and 1 (k=32)
    GLDS(Ag0, &As[0][segA0]);
    GLDS(Ag1, &As[0][segA1]);
    GLDS(Bg0, &Bs[0][segB]);
    GLDS(Ag0 + 32, &As[1][segA0]);
    GLDS(Ag1 + 32, &As[1][segA1]);
    GLDS(Bg0 + 32, &Bs[1][segB]);

#define QKV_COMPUTE(curslot) { \
        h16x8 af[4], bf[2]; \
        _Pragma("unroll") \
        for (int mt = 0; mt < 4; mt++) \
            af[mt] = *(const h16x8*)&As[curslot][(wm + mt * 16 + l16) * 32 + fcol]; \
        _Pragma("unroll") \
        for (int nt = 0; nt < 2; nt++) \
            bf[nt] = *(const h16x8*)&Bs[curslot][(wn + nt * 16 + l16) * 32 + fcol]; \
        _Pragma("unroll") \
        for (int mt = 0; mt < 4; mt++) \
            _Pragma("unroll") \
            for (int nt = 0; nt < 2; nt++) \
                acc[mt][nt] = MFMAH(af[mt], bf[nt], acc[mt][nt]); \
    }

    for (int k0 = 0; k0 < K; k0 += 64) {
        const int s0 = (k0 >> 5) & 3, s1 = (s0 + 1) & 3;
        const int s2 = (s0 + 2) & 3, s3 = (s0 + 3) & 3;
        __syncthreads();   // slots s0,s1 staged (issued last pair) now drained
        if (k0 + 64 < K) {
            GLDS(Ag0 + k0 + 64, &As[s2][segA0]);
            GLDS(Ag1 + k0 + 64, &As[s2][segA1]);
            GLDS(Bg0 + k0 + 64, &Bs[s2][segB]);
        }
        if (k0 + 96 < K) {
            GLDS(Ag0 + k0 + 96, &As[s3][segA0]);
            GLDS(Ag1 + k0 + 96, &As[s3][segA1]);
            GLDS(Bg0 + k0 + 96, &Bs[s3][segB]);
        }
        QKV_COMPUTE(s0);
        QKV_COMPUTE(s1);
    }
#undef QKV_COMPUTE

    if (colBase < 1024) {
        // ---- Q region: plain store to Qh (stride 1024)
#pragma unroll
        for (int mt = 0; mt < 4; mt++)
#pragma unroll
            for (int nt = 0; nt < 2; nt++) {
                const int row = rowBase + wm + mt * 16 + quad * 4;
                const int col = colBase + wn + nt * 16 + l16;
#pragma unroll
                for (int r = 0; r < 4; r++)
                    Qh[(size_t)(row + r) * D_MODEL + col] = f2h(acc[mt][nt][r]);
            }
    } else if (colBase < 1280) {
        // ---- K region: in-register rope (pair = acc[mt][0]/acc[mt][1])
        const int h = (colBase - 1024) >> 6;
        const int p = wn + l16;                 // [0,16) u [32,48)
        const int j = (p < 32) ? p : p - 16;    // [0,32)
#pragma unroll
        for (int mt = 0; mt < 4; mt++) {
            const int rowm = rowBase + wm + mt * 16 + quad * 4;
            const int bb = rowm >> 11, nb = rowm & (NN - 1);
            ushort_t* dstK = Kb + ((size_t)(bb * 4 + h) * NN) * 64;
#pragma unroll
            for (int r = 0; r < 4; r++) {
                const int n = nb + r;
                const float c = Cos[n * 32 + j], s = Sin[n * 32 + j];
                const float e = acc[mt][0][r], o = acc[mt][1][r];
                ushort_t* dk = dstK + (size_t)n * 64;
                dk[j]      = f2h(e * c - o * s);
                dk[j + 32] = f2h(e * s + o * c);
            }
        }
    } else {
        // ---- V region: transposed store to Vt (one uint2 per fragment)
        const int v0 = colBase - 1280;
#pragma unroll
        for (int mt = 0; mt < 4; mt++)
#pragma unroll
            for (int nt = 0; nt < 2; nt++) {
                const int d = v0 + wn + nt * 16 + l16;
                const int rowm = rowBase + wm + mt * 16 + quad * 4;
                const int bb = rowm >> 11, nb = rowm & (NN - 1);
                uint2 pk;
                pk.x = pk2h(acc[mt][nt][0], acc[mt][nt][1]);
                pk.y = pk2h(acc[mt][nt][2], acc[mt][nt][3]);
                *(uint2*)&Vt[((size_t)(bb * 256 + d)) * NN + nb] = pk;
            }
    }
}

// ---------------------------------------------------------------------------
// MFMA flash attention. Round-31 (= r18 theory with the GRID SIZE BUG
// fixed): grid is 512 blocks (8 qt x 16 h x 4 z), NOT 1024. XCD swizzle:
// 512 = 8 XCDs x 64; wrk = (L&7)*64 + (L>>3); decode qt=wrk&7,
// h=(wrk>>3)&15, z=wrk>>7 in [0,4). Each XCD owns 64 contiguous wrk =
// half a (b,chunk) slice (8 qt x 8 h = 2 kvh panels = 1MB K/V) ->
// L2-resident across its blocks. Inner loop = r17 kt-pair, staging = r14.
// ---------------------------------------------------------------------------
__global__ __launch_bounds__(256)
void attn_mfma(const ushort_t* __restrict__ Qh, const float* __restrict__ Cos,
               const float* __restrict__ Sin, const ushort_t* __restrict__ Kb,
               const ushort_t* __restrict__ Vt, ushort_t* __restrict__ Pnum,
               float* __restrict__ Pl)
{
    // XCD swizzle: 512 blocks = 8 XCDs x 64 contiguous work items
    const int L = blockIdx.x;
    const int wrk = (L & 7) * 64 + (L >> 3);
    const int qt = wrk & 7, h = (wrk >> 3) & 15, z = wrk >> 7;   // z in [0,4)
    const int b = z >> 1, chunk = z & 1;
    const int kvh = h >> 2;
    const int tid = threadIdx.x;
    const int wave = tid >> 6, lane = tid & 63;
    const int quad = lane >> 4, l16 = lane & 15;

    __shared__ ushort_t Ks[2][128][64];
    __shared__ ushort_t Vs[2][64][128];

    const int row0 = qt * 256 + wave * 64;
    const float SC = 0.125f * 1.44269504f;

    h16x8 qf[4][2];
#pragma unroll
    for (int mt = 0; mt < 4; mt++) {
        const int n = row0 + mt * 16 + l16;
        // pre-rope Q row: cols h*64 + [2j, 2j+1] for j = quad*8 + i
        const uint_t* pr =
            (const uint_t*)(Qh + (size_t)(b * NN + n) * D_MODEL + h * 64) + quad * 8;
        uint4 pa = *(const uint4*)pr;
        uint4 pc = *(const uint4*)(pr + 4);
        const uint_t pk[8] = {pa.x, pa.y, pa.z, pa.w, pc.x, pc.y, pc.z, pc.w};
        const float4 c0 = *(const float4*)&Cos[(size_t)n * 32 + quad * 8];
        const float4 c1 = *(const float4*)&Cos[(size_t)n * 32 + quad * 8 + 4];
        const float4 s0 = *(const float4*)&Sin[(size_t)n * 32 + quad * 8];
        const float4 s1 = *(const float4*)&Sin[(size_t)n * 32 + quad * 8 + 4];
        const float cc[8] = {c0.x, c0.y, c0.z, c0.w, c1.x, c1.y, c1.z, c1.w};
        const float ss[8] = {s0.x, s0.y, s0.z, s0.w, s1.x, s1.y, s1.z, s1.w};
#pragma unroll
        for (int i = 0; i < 8; i++) {
            const float e = h2f((ushort_t)pk[i]);
            const float o = h2f((ushort_t)(pk[i] >> 16));
            qf[mt][0][i] = (_Float16)((e * cc[i] - o * ss[i]) * SC);
            qf[mt][1][i] = (_Float16)((e * ss[i] + o * cc[i]) * SC);
        }
    }

    h16x4 ones;
#pragma unroll
    for (int i = 0; i < 4; i++) ones[i] = (_Float16)1.0f;

    const ushort_t* kbase = Kb + (size_t)(b * 4 + kvh) * NN * 64;
    const ushort_t* vbase = Vt + (size_t)(b * 256 + kvh * 64) * NN;
    const int key_lo = chunk * (NN / NSPLIT);          // 1024-key chunk
    const int rot = (qt + ((h & 3) << 2)) & (NTILE - 1);

    // staging lane constants (GLDS: dest = wave-uniform base + lane*16)
    const int krow = (wave << 3) + (lane >> 3);        // row within 32-row group
    const int kseg = (lane & 7) ^ (krow & 7);          // pre-swizzled global seg
    const ushort_t* kp_lane = kbase + (size_t)krow * 64 + kseg * 8;
    const int vrow = (wave << 2) + (lane >> 4);        // row within 16-row group
    const int vseg = (lane & 15) ^ (vrow & 7);
    const ushort_t* vp_lane = vbase + (size_t)vrow * NN + vseg * 8;

#define STAGE(key, bufidx) { \
        _Pragma("unroll") \
        for (int i = 0; i < 4; i++) { \
            GLDS(kp_lane + (size_t)((key) + i * 32) * 64, &Ks[bufidx][i * 32 + (wave << 3)][0]); \
            GLDS(vp_lane + (size_t)(i * 16) * NN + (key), &Vs[bufidx][i * 16 + (wave << 2)][0]); \
        } \
    }

    const f32x4 zz = {0.f, 0.f, 0.f, 0.f};
    f32x4 o[4][4];
#pragma unroll
    for (int mt = 0; mt < 4; mt++)
#pragma unroll
        for (int dt = 0; dt < 4; dt++) o[mt][dt] = zz;
    f32x4 lsum[4];
#pragma unroll
    for (int mt = 0; mt < 4; mt++) lsum[mt] = zz;

    // prologue: stage tile 0 into buf 0
    STAGE(key_lo + rot * KVBLK, 0);

    const int kswz = l16 & 7;

    for (int t = 0; t < NTILE; t++) {
        const int cur = t & 1, nxt = cur ^ 1;
        __syncthreads();   // drains GLDS for buf[cur]; prev compute (buf[nxt]) done
        if (t < NTILE - 1) {
            const int kn = key_lo + ((rot + t + 1) & (NTILE - 1)) * KVBLK;
            STAGE(kn, nxt);   // lands during compute below, drained next barrier
        }

        // ---- kt-PAIR pipeline: QK x2 -> exp x2 -> PV x2
#pragma unroll
        for (int kp = 0; kp < 4; kp++) {
            const int ka = kp * 2, kb2 = kp * 2 + 1;
            // fragment reads for both kts (issued together; one lgkm window)
            h16x8 kf0a = *(const h16x8*)&Ks[cur][ka * 16 + l16][(quad ^ kswz) << 3];
            h16x8 kf1a = *(const h16x8*)&Ks[cur][ka * 16 + l16][((4 + quad) ^ kswz) << 3];
            h16x8 kf0b = *(const h16x8*)&Ks[cur][kb2 * 16 + l16][(quad ^ kswz) << 3];
            h16x8 kf1b = *(const h16x8*)&Ks[cur][kb2 * 16 + l16][((4 + quad) ^ kswz) << 3];
            h16x4 vaa[4], vab[4];
#pragma unroll
            for (int dt = 0; dt < 4; dt++) {
                vaa[dt] = *(const h16x4*)&Vs[cur][dt * 16 + l16]
                    [(((ka * 2 + (quad >> 1)) ^ kswz) << 3) + ((quad & 1) << 2)];
                vab[dt] = *(const h16x4*)&Vs[cur][dt * 16 + l16]
                    [(((kb2 * 2 + (quad >> 1)) ^ kswz) << 3) + ((quad & 1) << 2)];
            }

            // QK for both kts: 8 independent MFMA chains
            f32x4 sta[4], stb[4];
#pragma unroll
            for (int mt = 0; mt < 4; mt++) {
                sta[mt] = MFMAH(kf0a, qf[mt][0], zz);
                stb[mt] = MFMAH(kf0b, qf[mt][0], zz);
            }
#pragma unroll
            for (int mt = 0; mt < 4; mt++) {
                sta[mt] = MFMAH(kf1a, qf[mt][1], sta[mt]);
                stb[mt] = MFMAH(kf1b, qf[mt][1], stb[mt]);
            }

            // exp + pack for both
            uint2 pba[4], pbb[4];
#pragma unroll
            for (int mt = 0; mt < 4; mt++) {
                pba[mt].x = pk2h(EXP2(sta[mt][0]), EXP2(sta[mt][1]));
                pba[mt].y = pk2h(EXP2(sta[mt][2]), EXP2(sta[mt][3]));
                pbb[mt].x = pk2h(EXP2(stb[mt][0]), EXP2(stb[mt][1]));
                pbb[mt].y = pk2h(EXP2(stb[mt][2]), EXP2(stb[mt][3]));
            }

            // PV for both kts
#pragma unroll
            for (int mt = 0; mt < 4; mt++) {
                const h16x4 pva = *(const h16x4*)&pba[mt];
                const h16x4 pvb = *(const h16x4*)&pbb[mt];
#pragma unroll
                for (int dt = 0; dt < 4; dt++) {
                    o[mt][dt] = MFMA16(vaa[dt], pva, o[mt][dt]);
                    o[mt][dt] = MFMA16(vab[dt], pvb, o[mt][dt]);
                }
                lsum[mt] = MFMA16(ones, pva, lsum[mt]);
                lsum[mt] = MFMA16(ones, pvb, lsum[mt]);
            }
        }
    }
#undef STAGE

    const size_t task0 = (size_t)(b * 16 + h) * NN + row0;
    ushort_t* np = Pnum + ((size_t)chunk * NTASK + task0) * 64;
#pragma unroll
    for (int mt = 0; mt < 4; mt++) {
        const float lt = lsum[mt][0];    // denom for q=l16 (rows identical)
        const float inv = 1.0f / lt;
#pragma unroll
        for (int dt = 0; dt < 4; dt++) {
            f32x4 v = o[mt][dt];
            uint2 pk;
            pk.x = pk2h(v[0] * inv, v[1] * inv);
            pk.y = pk2h(v[2] * inv, v[3] * inv);
            *(uint2*)&np[(size_t)(mt * 16 + l16) * 64 + dt * 16 + quad * 4] = pk;
        }
        if (quad == 0)
            Pl[(size_t)chunk * NTASK + task0 + mt * 16 + l16] = lt;
    }
}

// ---------------------------------------------------------------------------
// Split-K combine (2-way) + relayout to plain [row][D_MODEL] f16 matrix.
// ---------------------------------------------------------------------------
__global__ __launch_bounds__(256)
void combine_kernel(const ushort_t* __restrict__ Pnum, const float* __restrict__ Pl,
                    ushort_t* __restrict__ Ob)
{
    const uint_t i = blockIdx.x * 256 + threadIdx.x;   // 8-elem group, 524288 total
    const int row = i >> 7;            // 128 groups per 1024-col row
    const int g = i & 127;
    const int col0 = g * 8;
    const int h = col0 >> 6, d = col0 & 63;
    const int b = row >> 11, n = row & (NN - 1);
    const size_t task = ((size_t)(b * 16 + h) << 11) + n;

    float l[NSPLIT], tot = 0.f;
#pragma unroll
    for (int c = 0; c < NSPLIT; c++) { l[c] = Pl[(size_t)c * NTASK + task]; tot += l[c]; }
    const float inv = 1.f / tot;

    uint4 in[NSPLIT];
#pragma unroll
    for (int c = 0; c < NSPLIT; c++)
        in[c] = *(const uint4*)&Pnum[((size_t)c * NTASK + task) * 64 + d];

    uint4 out;
    uint_t* po = (uint_t*)&out;
#pragma unroll
    for (int j = 0; j < 4; j++) {
        float x = 0.f, y = 0.f;
#pragma unroll
        for (int c = 0; c < NSPLIT; c++) {
            const float w = l[c] * inv;
            fp16x2 u = *(const fp16x2*)&((const uint_t*)&in[c])[j];
            x += w * (float)u.x;
            y += w * (float)u.y;
        }
        po[j] = pk2h(x, y);
    }
    *(uint4*)&Ob[(size_t)row * D_MODEL + col0] = out;
}

// ---------------------------------------------------------------------------
// Wo GEMM: plain f16 GEMM (fp32 out), 128x64 tile, 4-slot ring + XCD-aware
// blockIdx swizzle (round-16 proven config).
// ---------------------------------------------------------------------------
__global__ __launch_bounds__(256)
void gemm_wo(const ushort_t* __restrict__ A, const ushort_t* __restrict__ Bt,
             float* __restrict__ C)
{
    __shared__ ushort_t As[4][128 * 32];
    __shared__ ushort_t Bs[4][64 * 32];

    const int tid  = threadIdx.x;
    const int wave = tid >> 6, lane = tid & 63;
    const int quad = lane >> 4, l16 = lane & 15;
    // XCD swizzle (512 = 8*64)
    const int L = blockIdx.x;
    const int wrk = (L & 7) * 64 + (L >> 3);
    const int rowBase = (wrk / 16) * 128, colBase = (wrk % 16) * 64;
    const int wm = (wave >> 1) * 64, wn = (wave & 1) * 32;

    f32x4 acc[4][2];
    const f32x4 zz = {0.f, 0.f, 0.f, 0.f};
#pragma unroll
    for (int i = 0; i < 4; i++)
#pragma unroll
        for (int j = 0; j < 2; j++) acc[i][j] = zz;

    const int sr = wave * 32 + (lane >> 2);
    const int sc = ((lane & 3) ^ ((lane >> 3) & 3)) * 8;
    const ushort_t* Ag0 = A + (size_t)(rowBase + sr) * D_MODEL + sc;
    const ushort_t* Ag1 = A + (size_t)(rowBase + sr + 16) * D_MODEL + sc;
    const int segA0 = (wave * 2 + 0) * 512, segA1 = (wave * 2 + 1) * 512;
    const int br = wave * 16 + (lane >> 2);
    const ushort_t* Bg0 = Bt + (size_t)(colBase + br) * D_MODEL + sc;
    const int segB = wave * 512;

    const int fcol = (quad ^ ((l16 >> 1) & 3)) * 8;

    GLDS(Ag0, &As[0][segA0]);
    GLDS(Ag1, &As[0][segA1]);
    GLDS(Bg0, &Bs[0][segB]);
    GLDS(Ag0 + 32, &As[1][segA0]);
    GLDS(Ag1 + 32, &As[1][segA1]);
    GLDS(Bg0 + 32, &Bs[1][segB]);

#define WO_COMPUTE(curslot) { \
        h16x8 af[4], bf[2]; \
        _Pragma("unroll") \
        for (int mt = 0; mt < 4; mt++) \
            af[mt] = *(const h16x8*)&As[curslot][(wm + mt * 16 + l16) * 32 + fcol]; \
        _Pragma("unroll") \
        for (int nt = 0; nt < 2; nt++) \
            bf[nt] = *(const h16x8*)&Bs[curslot][(wn + nt * 16 + l16) * 32 + fcol]; \
        _Pragma("unroll") \
        for (int mt = 0; mt < 4; mt++) \
            _Pragma("unroll") \
            for (int nt = 0; nt < 2; nt++) \
                acc[mt][nt] = MFMAH(af[mt], bf[nt], acc[mt][nt]); \
    }

    for (int k0 = 0; k0 < D_MODEL; k0 += 64) {
        const int s0 = (k0 >> 5) & 3, s1 = (s0 + 1) & 3;
        const int s2 = (s0 + 2) & 3, s3 = (s0 + 3) & 3;
        __syncthreads();
        if (k0 + 64 < D_MODEL) {
            GLDS(Ag0 + k0 + 64, &As[s2][segA0]);
            GLDS(Ag1 + k0 + 64, &As[s2][segA1]);
            GLDS(Bg0 + k0 + 64, &Bs[s2][segB]);
        }
        if (k0 + 96 < D_MODEL) {
            GLDS(Ag0 + k0 + 96, &As[s3][segA0]);
            GLDS(Ag1 + k0 + 96, &As[s3][segA1]);
            GLDS(Bg0 + k0 + 96, &Bs[s3][segB]);
        }
        WO_COMPUTE(s0);
        WO_COMPUTE(s1);
    }
#undef WO_COMPUTE

#pragma unroll
    for (int mt = 0; mt < 4; mt++)
#pragma unroll
        for (int nt = 0; nt < 2; nt++) {
            const int row = rowBase + wm + mt * 16 + quad * 4;
            const int col = colBase + wn + nt * 16 + l16;
#pragma unroll
            for (int r = 0; r < 4; r++)
                C[(size_t)(row + r) * D_MODEL + col] = acc[mt][nt][r];
        }
}

// ---------------------------------------------------------------------------
extern "C" void kernel_launch(void* const* d_in, const int* in_sizes, int n_in,
                              void* d_out, int out_size, void* d_ws, size_t ws_size,
                              hipStream_t stream)
{
    const float* x    = (const float*)d_in[0];
    const float* cosp = (const float*)d_in[1];
    const float* sinp = (const float*)d_in[2];
    const float* Wq   = (const float*)d_in[3];
    const float* Wk   = (const float*)d_in[4];
    const float* Wv   = (const float*)d_in[5];
    const float* Wo   = (const float*)d_in[6];

    char* w = (char*)d_ws;
    ushort_t* xb     = (ushort_t*)w;                       w += (size_t)MROWS * D_MODEL * 2;
    ushort_t* WqkvT  = (ushort_t*)w;                       w += (size_t)QKVN * D_MODEL * 2;
    ushort_t* WoT    = (ushort_t*)w;                       w += (size_t)D_MODEL * D_MODEL * 2;
    ushort_t* Qh     = (ushort_t*)w;                       w += (size_t)MROWS * D_MODEL * 2;
    ushort_t* Kbuf   = (ushort_t*)w;                       w += (size_t)MROWS * KVDIM * 2;
    ushort_t* Vt     = (ushort_t*)w;                       w += (size_t)MROWS * KVDIM * 2;
    ushort_t* Obuf   = (ushort_t*)w;                       w += (size_t)MROWS * D_MODEL * 2;
    ushort_t* Pnum   = (ushort_t*)w;                       w += (size_t)NSPLIT * NTASK * 64 * 2;
    float*    Pl     = (float*)w;

    // --- fused prep (cast + 4 transposes, K-weight rho-permute): 1 dispatch
    prep_kernel<<<6656, 256, 0, stream>>>(x, Wq, Wk, Wv, Wo, xb, WqkvT, WoT);

    // --- fused QKV projection + K-rope + V-transpose epilogue, XCD swizzle
    gemm_qkv<<<768, 256, 0, stream>>>(
        xb, WqkvT, cosp, sinp, Qh, Kbuf, Vt);

    // --- attention (split-K x2, XCD-aware grid, 512 blocks)
    attn_mfma<<<512, 256, 0, stream>>>(
        Qh, cosp, sinp, Kbuf, Vt, Pnum, Pl);

    // --- 2-way split-K combine -> plain f16 matrix
    combine_kernel<<<(MROWS * D_MODEL / 8) / 256, 256, 0, stream>>>(
        Pnum, Pl, Obuf);

    // --- output projection (plain GEMM, fp32 out), 4-slot ring, XCD swizzle
    gemm_wo<<<512, 256, 0, stream>>>(
        Obuf, WoT, (float*)d_out);
}

// Round 20
// 177.972 us; speedup vs baseline: 1.0444x; 1.0050x over previous
//
#include <hip/hip_runtime.h>
#include <math.h>

#define D_MODEL 1024
#define NHEADS  16
#define NKV     4
#define HDIM    64
#define KVDIM   256
#define BB      2
#define NN      2048
#define MROWS   (BB*NN)        // 4096
#define QKVN    1536           // 1024 + 256 + 256
#define NTASK   (MROWS*NHEADS) // 65536
#define NSPLIT  2
#define KVBLK   128
#define NTILE   ((NN/NSPLIT)/KVBLK)   // 8

typedef unsigned short ushort_t;
typedef unsigned int uint_t;
typedef float    f32x4 __attribute__((ext_vector_type(4)));
typedef _Float16 h16x8 __attribute__((ext_vector_type(8)));
typedef _Float16 h16x4 __attribute__((ext_vector_type(4)));
typedef __fp16   fp16x2 __attribute__((ext_vector_type(2)));

#define MFMAH(A,B,C)  __builtin_amdgcn_mfma_f32_16x16x32_f16((A),(B),(C),0,0,0)
// NOTE spelling: carried-forward GCN-era intrinsic has NO underscore before f16
#define MFMA16(A,B,C) __builtin_amdgcn_mfma_f32_16x16x16f16((A),(B),(C),0,0,0)
// raw v_exp_f32 (1 instr) -- libm exp2f carries a ~6-instr denormal fixup
#define EXP2(x) __builtin_amdgcn_exp2f(x)

// async global->LDS, 16B per lane; LDS dest = wave-uniform base + lane*16
#define GLDS(gp, lp) __builtin_amdgcn_global_load_lds( \
    (const __attribute__((address_space(1))) void*)(gp), \
    (__attribute__((address_space(3))) void*)(lp), 16, 0, 0)

__device__ __forceinline__ ushort_t f2h(float f) {
    _Float16 h = (_Float16)f;
    return *(ushort_t*)&h;
}
__device__ __forceinline__ float h2f(ushort_t u) {
    return (float)(*(const _Float16*)&u);
}
// two fp32 -> packed f16x2, single v_cvt_pkrtz_f16_f32
__device__ __forceinline__ uint_t pk2h(float a, float b) {
    fp16x2 v = __builtin_amdgcn_cvt_pkrtz(a, b);
    return *(uint_t*)&v;
}

// ---------------------------------------------------------------------------
// Fused prep: cast x->f16 (blocks [0,2048), 2 float4/thread) + 4 weight
// transpose-casts (blocks [2048,4608)). K-weight columns PERMUTED per head:
// rho(2j)=p, rho(2j+1)=p+16 with p=(j<16)?j:j+16 -- rope pair lands in the
// SAME LANE (nt=0/nt=1) of the QKV GEMM epilogue.
// ---------------------------------------------------------------------------
__global__ __launch_bounds__(256)
void prep_kernel(const float* __restrict__ x, const float* __restrict__ Wq,
                 const float* __restrict__ Wk, const float* __restrict__ Wv,
                 const float* __restrict__ Wo, ushort_t* __restrict__ xb,
                 ushort_t* __restrict__ WqkvT, ushort_t* __restrict__ WoT)
{
    __shared__ float T[32][33];
    int blk = blockIdx.x;
    if (blk < 2048) {                      // cast: 524288 uint4 groups
        const int i = blk * 256 + threadIdx.x;
        float4 v0 = ((const float4*)x)[2 * i];
        float4 v1 = ((const float4*)x)[2 * i + 1];
        uint4 o;
        o.x = pk2h(v0.x, v0.y);
        o.y = pk2h(v0.z, v0.w);
        o.z = pk2h(v1.x, v1.y);
        o.w = pk2h(v1.z, v1.w);
        ((uint4*)xb)[i] = o;
        return;
    }
    blk -= 2048;
    const float* src; ushort_t* dst; int N, bx, by; int kperm = 0;
    if (blk < 1024)      { src = Wq; dst = WqkvT;                            N = D_MODEL; bx = blk & 31; by = blk >> 5; }
    else if (blk < 1280) { blk -= 1024; src = Wk; dst = WqkvT + (size_t)1024 * D_MODEL; N = KVDIM; bx = blk & 7; by = blk >> 3; kperm = 1; }
    else if (blk < 1536) { blk -= 1280; src = Wv; dst = WqkvT + (size_t)1280 * D_MODEL; N = KVDIM; bx = blk & 7; by = blk >> 3; }
    else                 { blk -= 1536; src = Wo; dst = WoT;                 N = D_MODEL; bx = blk & 31; by = blk >> 5; }
    const int tx = threadIdx.x & 31, ty = threadIdx.x >> 5;
    const int n0 = bx * 32, k0 = by * 32;
#pragma unroll
    for (int i = 0; i < 4; i++)
        T[ty + i * 8][tx] = src[(size_t)(k0 + ty + i * 8) * N + n0 + tx];
    __syncthreads();
#pragma unroll
    for (int i = 0; i < 4; i++) {
        int c = n0 + ty + i * 8;
        if (kperm) {
            const int hd = c >> 6, ch = c & 63;
            const int j = ch >> 1, odd = ch & 1;
            const int p = ((j < 16) ? j : j + 16) + odd * 16;
            c = hd * 64 + p;
        }
        dst[(size_t)c * D_MODEL + k0 + tx] = f2h(T[tx][ty + i * 8]);
    }
}

// ---------------------------------------------------------------------------
// f16 MFMA GEMM for QKV, 128x64 tile, 4-slot LDS ring + XCD swizzle
// (round-16 proven config). Epilogue fusion: Q->Qh raw, K->rope in-register
// (rho-permuted weights), V->transposed Vt.
// ---------------------------------------------------------------------------
__global__ __launch_bounds__(256)
void gemm_qkv(const ushort_t* __restrict__ A, const ushort_t* __restrict__ Bt,
              const float* __restrict__ Cos, const float* __restrict__ Sin,
              ushort_t* __restrict__ Qh, ushort_t* __restrict__ Kb,
              ushort_t* __restrict__ Vt)
{
    __shared__ ushort_t As[4][128 * 32];
    __shared__ ushort_t Bs[4][64 * 32];

    const int K = D_MODEL;
    const int tid  = threadIdx.x;
    const int wave = tid >> 6, lane = tid & 63;
    const int quad = lane >> 4, l16 = lane & 15;
    // XCD swizzle: L%8 = XCD -> work w contiguous per XCD (768 = 8*96)
    const int L = blockIdx.x;
    const int wrk = (L & 7) * 96 + (L >> 3);
    const int rowBase = (wrk / 24) * 128, colBase = (wrk % 24) * 64;
    const int wm = (wave >> 1) * 64, wn = (wave & 1) * 32;

    f32x4 acc[4][2];
    const f32x4 zz = {0.f, 0.f, 0.f, 0.f};
#pragma unroll
    for (int i = 0; i < 4; i++)
#pragma unroll
        for (int j = 0; j < 2; j++) acc[i][j] = zz;

    const int sr = wave * 32 + (lane >> 2);
    const int sc = ((lane & 3) ^ ((lane >> 3) & 3)) * 8;
    const ushort_t* Ag0 = A + (size_t)(rowBase + sr) * K + sc;
    const ushort_t* Ag1 = A + (size_t)(rowBase + sr + 16) * K + sc;
    const int segA0 = (wave * 2 + 0) * 512, segA1 = (wave * 2 + 1) * 512;
    const int br = wave * 16 + (lane >> 2);
    const ushort_t* Bg0 = Bt + (size_t)(colBase + br) * K + sc;
    const int segB = wave * 512;

    const int fcol = (quad ^ ((l16 >> 1) & 3)) * 8;

    // prologue: stage slots 0 (k=0) and 1 (k=32)
    GLDS(Ag0, &As[0][segA0]);
    GLDS(Ag1, &As[0][segA1]);
    GLDS(Bg0, &Bs[0][segB]);
    GLDS(Ag0 + 32, &As[1][segA0]);
    GLDS(Ag1 + 32, &As[1][segA1]);
    GLDS(Bg0 + 32, &Bs[1][segB]);

#define QKV_COMPUTE(curslot) { \
        h16x8 af[4], bf[2]; \
        _Pragma("unroll") \
        for (int mt = 0; mt < 4; mt++) \
            af[mt] = *(const h16x8*)&As[curslot][(wm + mt * 16 + l16) * 32 + fcol]; \
        _Pragma("unroll") \
        for (int nt = 0; nt < 2; nt++) \
            bf[nt] = *(const h16x8*)&Bs[curslot][(wn + nt * 16 + l16) * 32 + fcol]; \
        _Pragma("unroll") \
        for (int mt = 0; mt < 4; mt++) \
            _Pragma("unroll") \
            for (int nt = 0; nt < 2; nt++) \
                acc[mt][nt] = MFMAH(af[mt], bf[nt], acc[mt][nt]); \
    }

    for (int k0 = 0; k0 < K; k0 += 64) {
        const int s0 = (k0 >> 5) & 3, s1 = (s0 + 1) & 3;
        const int s2 = (s0 + 2) & 3, s3 = (s0 + 3) & 3;
        __syncthreads();   // slots s0,s1 staged (issued last pair) now drained
        if (k0 + 64 < K) {
            GLDS(Ag0 + k0 + 64, &As[s2][segA0]);
            GLDS(Ag1 + k0 + 64, &As[s2][segA1]);
            GLDS(Bg0 + k0 + 64, &Bs[s2][segB]);
        }
        if (k0 + 96 < K) {
            GLDS(Ag0 + k0 + 96, &As[s3][segA0]);
            GLDS(Ag1 + k0 + 96, &As[s3][segA1]);
            GLDS(Bg0 + k0 + 96, &Bs[s3][segB]);
        }
        QKV_COMPUTE(s0);
        QKV_COMPUTE(s1);
    }
#undef QKV_COMPUTE

    if (colBase < 1024) {
        // ---- Q region: plain store to Qh (stride 1024)
#pragma unroll
        for (int mt = 0; mt < 4; mt++)
#pragma unroll
            for (int nt = 0; nt < 2; nt++) {
                const int row = rowBase + wm + mt * 16 + quad * 4;
                const int col = colBase + wn + nt * 16 + l16;
#pragma unroll
                for (int r = 0; r < 4; r++)
                    Qh[(size_t)(row + r) * D_MODEL + col] = f2h(acc[mt][nt][r]);
            }
    } else if (colBase < 1280) {
        // ---- K region: in-register rope (pair = acc[mt][0]/acc[mt][1])
        const int h = (colBase - 1024) >> 6;
        const int p = wn + l16;                 // [0,16) u [32,48)
        const int j = (p < 32) ? p : p - 16;    // [0,32)
#pragma unroll
        for (int mt = 0; mt < 4; mt++) {
            const int rowm = rowBase + wm + mt * 16 + quad * 4;
            const int bb = rowm >> 11, nb = rowm & (NN - 1);
            ushort_t* dstK = Kb + ((size_t)(bb * 4 + h) * NN) * 64;
#pragma unroll
            for (int r = 0; r < 4; r++) {
                const int n = nb + r;
                const float c = Cos[n * 32 + j], s = Sin[n * 32 + j];
                const float e = acc[mt][0][r], o = acc[mt][1][r];
                ushort_t* dk = dstK + (size_t)n * 64;
                dk[j]      = f2h(e * c - o * s);
                dk[j + 32] = f2h(e * s + o * c);
            }
        }
    } else {
        // ---- V region: transposed store to Vt (one uint2 per fragment)
        const int v0 = colBase - 1280;
#pragma unroll
        for (int mt = 0; mt < 4; mt++)
#pragma unroll
            for (int nt = 0; nt < 2; nt++) {
                const int d = v0 + wn + nt * 16 + l16;
                const int rowm = rowBase + wm + mt * 16 + quad * 4;
                const int bb = rowm >> 11, nb = rowm & (NN - 1);
                uint2 pk;
                pk.x = pk2h(acc[mt][nt][0], acc[mt][nt][1]);
                pk.y = pk2h(acc[mt][nt][2], acc[mt][nt][3]);
                *(uint2*)&Vt[((size_t)(bb * 256 + d)) * NN + nb] = pk;
            }
    }
}

// ---------------------------------------------------------------------------
// MFMA flash attention (round-19 winner) + lsum fold: per kt-pair, psum =
// pva + pvb via v_pk_add_f16 (values <=2, f16-exact regime), then ONE
// lsum MFMA16 instead of two -- removes 16 MFMA16/tile from the 40%-busy
// matrix pipe. XCD-aware 512-block grid (each XCD owns 64 contiguous wrk
// = 2 kvh panels = 1MB K/V, L2-resident: FETCH 25.7 -> 12.4MB measured).
// ---------------------------------------------------------------------------
__global__ __launch_bounds__(256)
void attn_mfma(const ushort_t* __restrict__ Qh, const float* __restrict__ Cos,
               const float* __restrict__ Sin, const ushort_t* __restrict__ Kb,
               const ushort_t* __restrict__ Vt, ushort_t* __restrict__ Pnum,
               float* __restrict__ Pl)
{
    // XCD swizzle: 512 blocks = 8 XCDs x 64 contiguous work items
    const int L = blockIdx.x;
    const int wrk = (L & 7) * 64 + (L >> 3);
    const int qt = wrk & 7, h = (wrk >> 3) & 15, z = wrk >> 7;   // z in [0,4)
    const int b = z >> 1, chunk = z & 1;
    const int kvh = h >> 2;
    const int tid = threadIdx.x;
    const int wave = tid >> 6, lane = tid & 63;
    const int quad = lane >> 4, l16 = lane & 15;

    __shared__ ushort_t Ks[2][128][64];
    __shared__ ushort_t Vs[2][64][128];

    const int row0 = qt * 256 + wave * 64;
    const float SC = 0.125f * 1.44269504f;

    h16x8 qf[4][2];
#pragma unroll
    for (int mt = 0; mt < 4; mt++) {
        const int n = row0 + mt * 16 + l16;
        // pre-rope Q row: cols h*64 + [2j, 2j+1] for j = quad*8 + i
        const uint_t* pr =
            (const uint_t*)(Qh + (size_t)(b * NN + n) * D_MODEL + h * 64) + quad * 8;
        uint4 pa = *(const uint4*)pr;
        uint4 pc = *(const uint4*)(pr + 4);
        const uint_t pk[8] = {pa.x, pa.y, pa.z, pa.w, pc.x, pc.y, pc.z, pc.w};
        const float4 c0 = *(const float4*)&Cos[(size_t)n * 32 + quad * 8];
        const float4 c1 = *(const float4*)&Cos[(size_t)n * 32 + quad * 8 + 4];
        const float4 s0 = *(const float4*)&Sin[(size_t)n * 32 + quad * 8];
        const float4 s1 = *(const float4*)&Sin[(size_t)n * 32 + quad * 8 + 4];
        const float cc[8] = {c0.x, c0.y, c0.z, c0.w, c1.x, c1.y, c1.z, c1.w};
        const float ss[8] = {s0.x, s0.y, s0.z, s0.w, s1.x, s1.y, s1.z, s1.w};
#pragma unroll
        for (int i = 0; i < 8; i++) {
            const float e = h2f((ushort_t)pk[i]);
            const float o = h2f((ushort_t)(pk[i] >> 16));
            qf[mt][0][i] = (_Float16)((e * cc[i] - o * ss[i]) * SC);
            qf[mt][1][i] = (_Float16)((e * ss[i] + o * cc[i]) * SC);
        }
    }

    h16x4 ones;
#pragma unroll
    for (int i = 0; i < 4; i++) ones[i] = (_Float16)1.0f;

    const ushort_t* kbase = Kb + (size_t)(b * 4 + kvh) * NN * 64;
    const ushort_t* vbase = Vt + (size_t)(b * 256 + kvh * 64) * NN;
    const int key_lo = chunk * (NN / NSPLIT);          // 1024-key chunk
    const int rot = (qt + ((h & 3) << 2)) & (NTILE - 1);

    // staging lane constants (GLDS: dest = wave-uniform base + lane*16)
    const int krow = (wave << 3) + (lane >> 3);        // row within 32-row group
    const int kseg = (lane & 7) ^ (krow & 7);          // pre-swizzled global seg
    const ushort_t* kp_lane = kbase + (size_t)krow * 64 + kseg * 8;
    const int vrow = (wave << 2) + (lane >> 4);        // row within 16-row group
    const int vseg = (lane & 15) ^ (vrow & 7);
    const ushort_t* vp_lane = vbase + (size_t)vrow * NN + vseg * 8;

#define STAGE(key, bufidx) { \
        _Pragma("unroll") \
        for (int i = 0; i < 4; i++) { \
            GLDS(kp_lane + (size_t)((key) + i * 32) * 64, &Ks[bufidx][i * 32 + (wave << 3)][0]); \
            GLDS(vp_lane + (size_t)(i * 16) * NN + (key), &Vs[bufidx][i * 16 + (wave << 2)][0]); \
        } \
    }

    const f32x4 zz = {0.f, 0.f, 0.f, 0.f};
    f32x4 o[4][4];
#pragma unroll
    for (int mt = 0; mt < 4; mt++)
#pragma unroll
        for (int dt = 0; dt < 4; dt++) o[mt][dt] = zz;
    f32x4 lsum[4];
#pragma unroll
    for (int mt = 0; mt < 4; mt++) lsum[mt] = zz;

    // prologue: stage tile 0 into buf 0
    STAGE(key_lo + rot * KVBLK, 0);

    const int kswz = l16 & 7;

    for (int t = 0; t < NTILE; t++) {
        const int cur = t & 1, nxt = cur ^ 1;
        __syncthreads();   // drains GLDS for buf[cur]; prev compute (buf[nxt]) done
        if (t < NTILE - 1) {
            const int kn = key_lo + ((rot + t + 1) & (NTILE - 1)) * KVBLK;
            STAGE(kn, nxt);   // lands during compute below, drained next barrier
        }

        // ---- kt-PAIR pipeline: QK x2 -> exp x2 -> PV x2
#pragma unroll
        for (int kp = 0; kp < 4; kp++) {
            const int ka = kp * 2, kb2 = kp * 2 + 1;
            // fragment reads for both kts (issued together; one lgkm window)
            h16x8 kf0a = *(const h16x8*)&Ks[cur][ka * 16 + l16][(quad ^ kswz) << 3];
            h16x8 kf1a = *(const h16x8*)&Ks[cur][ka * 16 + l16][((4 + quad) ^ kswz) << 3];
            h16x8 kf0b = *(const h16x8*)&Ks[cur][kb2 * 16 + l16][(quad ^ kswz) << 3];
            h16x8 kf1b = *(const h16x8*)&Ks[cur][kb2 * 16 + l16][((4 + quad) ^ kswz) << 3];
            h16x4 vaa[4], vab[4];
#pragma unroll
            for (int dt = 0; dt < 4; dt++) {
                vaa[dt] = *(const h16x4*)&Vs[cur][dt * 16 + l16]
                    [(((ka * 2 + (quad >> 1)) ^ kswz) << 3) + ((quad & 1) << 2)];
                vab[dt] = *(const h16x4*)&Vs[cur][dt * 16 + l16]
                    [(((kb2 * 2 + (quad >> 1)) ^ kswz) << 3) + ((quad & 1) << 2)];
            }

            // QK for both kts: 8 independent MFMA chains
            f32x4 sta[4], stb[4];
#pragma unroll
            for (int mt = 0; mt < 4; mt++) {
                sta[mt] = MFMAH(kf0a, qf[mt][0], zz);
                stb[mt] = MFMAH(kf0b, qf[mt][0], zz);
            }
#pragma unroll
            for (int mt = 0; mt < 4; mt++) {
                sta[mt] = MFMAH(kf1a, qf[mt][1], sta[mt]);
                stb[mt] = MFMAH(kf1b, qf[mt][1], stb[mt]);
            }

            // exp + pack for both
            uint2 pba[4], pbb[4];
#pragma unroll
            for (int mt = 0; mt < 4; mt++) {
                pba[mt].x = pk2h(EXP2(sta[mt][0]), EXP2(sta[mt][1]));
                pba[mt].y = pk2h(EXP2(sta[mt][2]), EXP2(sta[mt][3]));
                pbb[mt].x = pk2h(EXP2(stb[mt][0]), EXP2(stb[mt][1]));
                pbb[mt].y = pk2h(EXP2(stb[mt][2]), EXP2(stb[mt][3]));
            }

            // PV for both kts; lsum folded: one MFMA16 on psum = pva+pvb
#pragma unroll
            for (int mt = 0; mt < 4; mt++) {
                const h16x4 pva = *(const h16x4*)&pba[mt];
                const h16x4 pvb = *(const h16x4*)&pbb[mt];
#pragma unroll
                for (int dt = 0; dt < 4; dt++) {
                    o[mt][dt] = MFMA16(vaa[dt], pva, o[mt][dt]);
                    o[mt][dt] = MFMA16(vab[dt], pvb, o[mt][dt]);
                }
                const h16x4 psum = pva + pvb;   // v_pk_add_f16 x2, values <= 2
                lsum[mt] = MFMA16(ones, psum, lsum[mt]);
            }
        }
    }
#undef STAGE

    const size_t task0 = (size_t)(b * 16 + h) * NN + row0;
    ushort_t* np = Pnum + ((size_t)chunk * NTASK + task0) * 64;
#pragma unroll
    for (int mt = 0; mt < 4; mt++) {
        const float lt = lsum[mt][0];    // denom for q=l16 (rows identical)
        const float inv = 1.0f / lt;
#pragma unroll
        for (int dt = 0; dt < 4; dt++) {
            f32x4 v = o[mt][dt];
            uint2 pk;
            pk.x = pk2h(v[0] * inv, v[1] * inv);
            pk.y = pk2h(v[2] * inv, v[3] * inv);
            *(uint2*)&np[(size_t)(mt * 16 + l16) * 64 + dt * 16 + quad * 4] = pk;
        }
        if (quad == 0)
            Pl[(size_t)chunk * NTASK + task0 + mt * 16 + l16] = lt;
    }
}

// ---------------------------------------------------------------------------
// Split-K combine (2-way) + relayout to plain [row][D_MODEL] f16 matrix.
// ---------------------------------------------------------------------------
__global__ __launch_bounds__(256)
void combine_kernel(const ushort_t* __restrict__ Pnum, const float* __restrict__ Pl,
                    ushort_t* __restrict__ Ob)
{
    const uint_t i = blockIdx.x * 256 + threadIdx.x;   // 8-elem group, 524288 total
    const int row = i >> 7;            // 128 groups per 1024-col row
    const int g = i & 127;
    const int col0 = g * 8;
    const int h = col0 >> 6, d = col0 & 63;
    const int b = row >> 11, n = row & (NN - 1);
    const size_t task = ((size_t)(b * 16 + h) << 11) + n;

    float l[NSPLIT], tot = 0.f;
#pragma unroll
    for (int c = 0; c < NSPLIT; c++) { l[c] = Pl[(size_t)c * NTASK + task]; tot += l[c]; }
    const float inv = 1.f / tot;

    uint4 in[NSPLIT];
#pragma unroll
    for (int c = 0; c < NSPLIT; c++)
        in[c] = *(const uint4*)&Pnum[((size_t)c * NTASK + task) * 64 + d];

    uint4 out;
    uint_t* po = (uint_t*)&out;
#pragma unroll
    for (int j = 0; j < 4; j++) {
        float x = 0.f, y = 0.f;
#pragma unroll
        for (int c = 0; c < NSPLIT; c++) {
            const float w = l[c] * inv;
            fp16x2 u = *(const fp16x2*)&((const uint_t*)&in[c])[j];
            x += w * (float)u.x;
            y += w * (float)u.y;
        }
        po[j] = pk2h(x, y);
    }
    *(uint4*)&Ob[(size_t)row * D_MODEL + col0] = out;
}

// ---------------------------------------------------------------------------
// Wo GEMM: plain f16 GEMM (fp32 out), 128x64 tile, 4-slot ring + XCD-aware
// blockIdx swizzle (round-16 proven config).
// ---------------------------------------------------------------------------
__global__ __launch_bounds__(256)
void gemm_wo(const ushort_t* __restrict__ A, const ushort_t* __restrict__ Bt,
             float* __restrict__ C)
{
    __shared__ ushort_t As[4][128 * 32];
    __shared__ ushort_t Bs[4][64 * 32];

    const int tid  = threadIdx.x;
    const int wave = tid >> 6, lane = tid & 63;
    const int quad = lane >> 4, l16 = lane & 15;
    // XCD swizzle (512 = 8*64)
    const int L = blockIdx.x;
    const int wrk = (L & 7) * 64 + (L >> 3);
    const int rowBase = (wrk / 16) * 128, colBase = (wrk % 16) * 64;
    const int wm = (wave >> 1) * 64, wn = (wave & 1) * 32;

    f32x4 acc[4][2];
    const f32x4 zz = {0.f, 0.f, 0.f, 0.f};
#pragma unroll
    for (int i = 0; i < 4; i++)
#pragma unroll
        for (int j = 0; j < 2; j++) acc[i][j] = zz;

    const int sr = wave * 32 + (lane >> 2);
    const int sc = ((lane & 3) ^ ((lane >> 3) & 3)) * 8;
    const ushort_t* Ag0 = A + (size_t)(rowBase + sr) * D_MODEL + sc;
    const ushort_t* Ag1 = A + (size_t)(rowBase + sr + 16) * D_MODEL + sc;
    const int segA0 = (wave * 2 + 0) * 512, segA1 = (wave * 2 + 1) * 512;
    const int br = wave * 16 + (lane >> 2);
    const ushort_t* Bg0 = Bt + (size_t)(colBase + br) * D_MODEL + sc;
    const int segB = wave * 512;

    const int fcol = (quad ^ ((l16 >> 1) & 3)) * 8;

    GLDS(Ag0, &As[0][segA0]);
    GLDS(Ag1, &As[0][segA1]);
    GLDS(Bg0, &Bs[0][segB]);
    GLDS(Ag0 + 32, &As[1][segA0]);
    GLDS(Ag1 + 32, &As[1][segA1]);
    GLDS(Bg0 + 32, &Bs[1][segB]);

#define WO_COMPUTE(curslot) { \
        h16x8 af[4], bf[2]; \
        _Pragma("unroll") \
        for (int mt = 0; mt < 4; mt++) \
            af[mt] = *(const h16x8*)&As[curslot][(wm + mt * 16 + l16) * 32 + fcol]; \
        _Pragma("unroll") \
        for (int nt = 0; nt < 2; nt++) \
            bf[nt] = *(const h16x8*)&Bs[curslot][(wn + nt * 16 + l16) * 32 + fcol]; \
        _Pragma("unroll") \
        for (int mt = 0; mt < 4; mt++) \
            _Pragma("unroll") \
            for (int nt = 0; nt < 2; nt++) \
                acc[mt][nt] = MFMAH(af[mt], bf[nt], acc[mt][nt]); \
    }

    for (int k0 = 0; k0 < D_MODEL; k0 += 64) {
        const int s0 = (k0 >> 5) & 3, s1 = (s0 + 1) & 3;
        const int s2 = (s0 + 2) & 3, s3 = (s0 + 3) & 3;
        __syncthreads();
        if (k0 + 64 < D_MODEL) {
            GLDS(Ag0 + k0 + 64, &As[s2][segA0]);
            GLDS(Ag1 + k0 + 64, &As[s2][segA1]);
            GLDS(Bg0 + k0 + 64, &Bs[s2][segB]);
        }
        if (k0 + 96 < D_MODEL) {
            GLDS(Ag0 + k0 + 96, &As[s3][segA0]);
            GLDS(Ag1 + k0 + 96, &As[s3][segA1]);
            GLDS(Bg0 + k0 + 96, &Bs[s3][segB]);
        }
        WO_COMPUTE(s0);
        WO_COMPUTE(s1);
    }
#undef WO_COMPUTE

#pragma unroll
    for (int mt = 0; mt < 4; mt++)
#pragma unroll
        for (int nt = 0; nt < 2; nt++) {
            const int row = rowBase + wm + mt * 16 + quad * 4;
            const int col = colBase + wn + nt * 16 + l16;
#pragma unroll
            for (int r = 0; r < 4; r++)
                C[(size_t)(row + r) * D_MODEL + col] = acc[mt][nt][r];
        }
}

// ---------------------------------------------------------------------------
extern "C" void kernel_launch(void* const* d_in, const int* in_sizes, int n_in,
                              void* d_out, int out_size, void* d_ws, size_t ws_size,
                              hipStream_t stream)
{
    const float* x    = (const float*)d_in[0];
    const float* cosp = (const float*)d_in[1];
    const float* sinp = (const float*)d_in[2];
    const float* Wq   = (const float*)d_in[3];
    const float* Wk   = (const float*)d_in[4];
    const float* Wv   = (const float*)d_in[5];
    const float* Wo   = (const float*)d_in[6];

    char* w = (char*)d_ws;
    ushort_t* xb     = (ushort_t*)w;                       w += (size_t)MROWS * D_MODEL * 2;
    ushort_t* WqkvT  = (ushort_t*)w;                       w += (size_t)QKVN * D_MODEL * 2;
    ushort_t* WoT    = (ushort_t*)w;                       w += (size_t)D_MODEL * D_MODEL * 2;
    ushort_t* Qh     = (ushort_t*)w;                       w += (size_t)MROWS * D_MODEL * 2;
    ushort_t* Kbuf   = (ushort_t*)w;                       w += (size_t)MROWS * KVDIM * 2;
    ushort_t* Vt     = (ushort_t*)w;                       w += (size_t)MROWS * KVDIM * 2;
    ushort_t* Obuf   = (ushort_t*)w;                       w += (size_t)MROWS * D_MODEL * 2;
    ushort_t* Pnum   = (ushort_t*)w;                       w += (size_t)NSPLIT * NTASK * 64 * 2;
    float*    Pl     = (float*)w;

    // --- fused prep (cast 2xfloat4/thread + 4 transposes, K rho-permute)
    prep_kernel<<<4608, 256, 0, stream>>>(x, Wq, Wk, Wv, Wo, xb, WqkvT, WoT);

    // --- fused QKV projection + K-rope + V-transpose epilogue, XCD swizzle
    gemm_qkv<<<768, 256, 0, stream>>>(
        xb, WqkvT, cosp, sinp, Qh, Kbuf, Vt);

    // --- attention (split-K x2, XCD-aware grid, lsum folded)
    attn_mfma<<<512, 256, 0, stream>>>(
        Qh, cosp, sinp, Kbuf, Vt, Pnum, Pl);

    // --- 2-way split-K combine -> plain f16 matrix
    combine_kernel<<<(MROWS * D_MODEL / 8) / 256, 256, 0, stream>>>(
        Pnum, Pl, Obuf);

    // --- output projection (plain GEMM, fp32 out), 4-slot ring, XCD swizzle
    gemm_wo<<<512, 256, 0, stream>>>(
        Obuf, WoT, (float*)d_out);
}